// Round 12
// baseline (525.605 us; speedup 1.0000x reference)
//
#include <hip/hip_runtime.h>

typedef __bf16 bf16_t;
typedef __bf16 bf16x8 __attribute__((ext_vector_type(8)));
typedef __bf16 bf16x4 __attribute__((ext_vector_type(4)));
typedef __bf16 bf16x2 __attribute__((ext_vector_type(2)));
typedef float f32x4 __attribute__((ext_vector_type(4)));

#define DEV __device__ __forceinline__
#define MFMA16 __builtin_amdgcn_mfma_f32_16x16x32_bf16

constexpr int Bb = 2, Ls = 512, Dd = 1024, Hh = 16, HD = 64, Mm = 16384, TK = 8;
constexpr int KSPLIT = 4;          // key splits for topk occupancy
constexpr int CAP = 40;            // candidate buffer per (query, split); E[count]~9
constexpr int NQ = Bb * Ls * Hh;   // 16384 query-heads; bh-major qid = (b*16+h)*512 + l
constexpr int CH = 4;              // attention chunks: mem 16x4 tiles; local causal on chunk 0

// f32-unit workspace layout (~43.3 MB; >=47.3 MB known available)
constexpr size_t OFF_QF   = 0;                                    // Q f32 [NQ][64]
constexpr size_t OFF_KH2  = OFF_QF + (size_t)NQ * HD;             // K hi bf16 [NQ][64]
constexpr size_t OFF_KL2  = OFF_KH2 + (size_t)NQ * HD / 2;        // K lo bf16
constexpr size_t OFF_VH2  = OFF_KL2 + (size_t)NQ * HD / 2;        // V hi bf16
constexpr size_t OFF_VL2  = OFF_VH2 + (size_t)NQ * HD / 2;        // V lo bf16
constexpr size_t OFF_QH   = OFF_VL2 + (size_t)NQ * HD / 2;        // Q hi bf16 [NQ][64]
constexpr size_t OFF_QL   = OFF_QH + (size_t)NQ * HD / 2;         // Q lo bf16
constexpr size_t OFF_KHG  = OFF_QL + (size_t)NQ * HD / 2;         // mem keys hi bf16 [M][64]
constexpr size_t OFF_FCAND = OFF_KHG + (size_t)Mm * HD / 2;       // int [KSPLIT][NQ][CAP]
constexpr size_t OFF_FCNT  = OFF_FCAND + (size_t)KSPLIT * NQ * CAP; // int [KSPLIT][NQ]
constexpr size_t OFF_F8   = OFF_FCNT + (size_t)KSPLIT * NQ;       // int [NQ][8]
constexpr size_t OFF_ML   = OFF_F8 + (size_t)NQ * TK;             // (m,l) [CH][NQ][2]
constexpr size_t OFF_PA   = OFF_ML + (size_t)CH * NQ * 2;         // acc [3][NQ][64] (chunk 3 aliased)
constexpr size_t WS_ELEMS = OFF_PA + (size_t)3 * NQ * HD + 16;
constexpr size_t WS_BYTES = WS_ELEMS * 4;

// aliases into FCAND region (dead after rescore8; written by prep_kv2 / flash)
constexpr size_t OFF_GKL = OFF_FCAND;                             // mem keys lo bf16 [M][64]
constexpr size_t OFF_GVH = OFF_GKL + (size_t)Mm * HD / 2;         // mem vals hi bf16
constexpr size_t OFF_GVL = OFF_GVH + (size_t)Mm * HD / 2;         // mem vals lo bf16
constexpr size_t OFF_PA3 = OFF_GVL + (size_t)Mm * HD / 2;         // acc chunk 3 [NQ][64] f32
static_assert(OFF_PA3 + (size_t)NQ * HD <= OFF_FCNT, "PA3 alias fits in FCAND");

DEV void ld8f(const float* p, float* dst) {
  float4 a = *(const float4*)p, b = *(const float4*)(p + 4);
  dst[0]=a.x; dst[1]=a.y; dst[2]=a.z; dst[3]=a.w;
  dst[4]=b.x; dst[5]=b.y; dst[6]=b.z; dst[7]=b.w;
}

DEV void split8(const float* av, bf16x8& hi, bf16x8& lo) {
#pragma unroll
  for (int j = 0; j < 8; ++j) {
    bf16_t h_ = (bf16_t)av[j];
    hi[j] = h_;
    lo[j] = (bf16_t)(av[j] - (float)h_);
  }
}

// 8B-aligned bf16x8 load (rows of stride-68 bf16 arrays are 8B- but not 16B-aligned)
DEV bf16x8 ld8h(const bf16_t* p) {
  bf16x4 a = *(const bf16x4*)p;
  bf16x4 b = *(const bf16x4*)(p + 4);
  bf16x8 r;
#pragma unroll
  for (int i = 0; i < 4; ++i) { r[i] = a[i]; r[i + 4] = b[i]; }
  return r;
}

// concat two 4xbf16 (as u64) into a bf16x8 MFMA fragment
DEV bf16x8 cat8(unsigned long long lo, unsigned long long hi) {
  bf16x8 r;
  __builtin_memcpy(&r, &lo, 8);
  __builtin_memcpy(reinterpret_cast<char*>(&r) + 8, &hi, 8);
  return r;
}

__global__ __launch_bounds__(256) void ws_sentinel(float* __restrict__ out, int n, float v) {
  int i = blockIdx.x * 256 + threadIdx.x;
  if (i < n) out[i] = v;
}

// ---------------- Kernel 0: pre-convert memory keys to bf16 hi (once) ----------------
__global__ __launch_bounds__(256) void prep_keys(const float* __restrict__ mk,
                                                 bf16_t* __restrict__ khg) {
  const size_t i = ((size_t)blockIdx.x * 256 + threadIdx.x) * 8;
  float v[8]; ld8f(mk + i, v);
  bf16x8 h;
#pragma unroll
  for (int j = 0; j < 8; ++j) h[j] = (bf16_t)v[j];
  *(bf16x8*)(khg + i) = h;
}

// ---------------- Kernel 0b: pre-split mem keys lo + mem values hi/lo (after rescore8) ----------------
__global__ __launch_bounds__(256) void prep_kv2(const float* __restrict__ mk,
                                                const float* __restrict__ mv,
                                                bf16_t* __restrict__ gkl,
                                                bf16_t* __restrict__ gvh,
                                                bf16_t* __restrict__ gvl) {
  const size_t i = ((size_t)blockIdx.x * 256 + threadIdx.x) * 8;
  float a[8]; ld8f(mk + i, a);
  float b[8]; ld8f(mv + i, b);
  bf16x8 kl, vh, vl;
#pragma unroll
  for (int j = 0; j < 8; ++j) {
    bf16_t kh_ = (bf16_t)a[j];
    kl[j] = (bf16_t)(a[j] - (float)kh_);
    bf16_t vh_ = (bf16_t)b[j];
    vh[j] = vh_;
    vl[j] = (bf16_t)(b[j] - (float)vh_);
  }
  *(bf16x8*)(gkl + i) = kl;
  *(bf16x8*)(gvh + i) = vh;
  *(bf16x8*)(gvl + i) = vl;
}

// ---------------- Kernel 1: QKV projection, W-tile LDS staged, 3-term split MFMA ----------------
__global__ __launch_bounds__(256) void qkv_mfma(
    const float* __restrict__ x,
    const float* __restrict__ Wq, const float* __restrict__ bq,
    const float* __restrict__ Wk, const float* __restrict__ bk,
    const float* __restrict__ Wv, const float* __restrict__ bv,
    float* __restrict__ qf, bf16_t* __restrict__ qhp, bf16_t* __restrict__ qlp,
    bf16_t* __restrict__ kh2, bf16_t* __restrict__ kl2,
    bf16_t* __restrict__ vh2, bf16_t* __restrict__ vl2) {
  __shared__ __align__(16) bf16_t WHs[2][64][40];   // 10240 B
  __shared__ __align__(16) bf16_t WLs[2][64][40];   // 10240 B
  const int z = blockIdx.z;
  const float* W    = (z == 0) ? Wq : ((z == 1) ? Wk : Wv);
  const float* bias = (z == 0) ? bq : ((z == 1) ? bk : bv);
  const int tid = threadIdx.x;
  const int lane = tid & 63, wv = tid >> 6;
  const int l15 = lane & 15, quad = lane >> 4;
  const int mrow = blockIdx.x * 64 + wv * 16 + l15;
  const int ncol0 = blockIdx.y * 64;
  const int srow = tid >> 2, scol = (tid & 3) * 8;  // staging: 64 rows x 32 k, 8 f32/thread
  f32x4 acc[4] = {};
  const size_t abase = (size_t)mrow * Dd + quad * 8;
  const size_t wbase = (size_t)(ncol0 + srow) * Dd + scol;
  {
    float wv8[8]; ld8f(W + wbase, wv8);
    bf16x8 h, l; split8(wv8, h, l);
    *(bf16x8*)&WHs[0][srow][scol] = h;
    *(bf16x8*)&WLs[0][srow][scol] = l;
  }
  int p = 0;
  for (int kk = 0; kk < Dd; kk += 32) {
    __syncthreads();
    if (kk + 32 < Dd) {
      float wv8[8]; ld8f(W + wbase + kk + 32, wv8);
      bf16x8 h, l; split8(wv8, h, l);
      *(bf16x8*)&WHs[p ^ 1][srow][scol] = h;
      *(bf16x8*)&WLs[p ^ 1][srow][scol] = l;
    }
    float av[8]; ld8f(x + abase + kk, av);
    bf16x8 ahi, alo; split8(av, ahi, alo);
#pragma unroll
    for (int t = 0; t < 4; ++t) {
      const bf16x8 bhi = *(const bf16x8*)&WHs[p][t * 16 + l15][quad * 8];
      const bf16x8 blo = *(const bf16x8*)&WLs[p][t * 16 + l15][quad * 8];
      acc[t] = MFMA16(ahi, bhi, acc[t], 0, 0, 0);
      acc[t] = MFMA16(alo, bhi, acc[t], 0, 0, 0);
      acc[t] = MFMA16(ahi, blo, acc[t], 0, 0, 0);
    }
    p ^= 1;
  }
#pragma unroll
  for (int t = 0; t < 4; ++t) {
    int col = ncol0 + t * 16 + l15;
    int h = col >> 6, hd = col & 63;
    float bb = bias[col];
#pragma unroll
    for (int r = 0; r < 4; ++r) {
      int row = blockIdx.x * 64 + wv * 16 + quad * 4 + r;   // token row = b*512+l
      int b = row >> 9, l = row & 511;
      float val = acc[t][r] + bb;
      size_t o = ((size_t)(b * Hh + h) * Ls + l) * HD + hd;
      if (z == 0) {
        qf[o] = val;
        bf16_t hv = (bf16_t)val;
        qhp[o] = hv;
        qlp[o] = (bf16_t)(val - (float)hv);
      } else {
        bf16_t hv = (bf16_t)val;
        bf16_t lv = (bf16_t)(val - (float)hv);
        if (z == 1) { kh2[o] = hv; kl2[o] = lv; }
        else        { vh2[o] = hv; vl2[o] = lv; }
      }
    }
  }
}

// ---------------- Kernel 2: threshold-filter coarse top-k, 8-wave TLP ----------------
// grid (256, 4), block 512 (8 waves). Per-wave inner structure IDENTICAL to the proven
// R2 form (same MFMA fragments, shfl reduce, insertion, single exact threshold) -- only
// the wave count doubles. Resources allowed 8 waves/SIMD (VGPR 44, LDS ~27KB) but the
// 4-wave blocks supplied only 4/SIMD (Occupancy 43%, busy-sum 56% -> latency-bound).
// Now: 1024 blocks x 8 waves = 4 blocks/CU x 8 waves = 32 waves/CU (HW max).
// Tile = 128 keys (8 waves x 16 rows), NT = 32. R4's failed variant split BLOCKS
// (doubling fixed cost + splitting the threshold); this shares one threshold/structure.
__global__ __launch_bounds__(512) void topk_thresh(
    const bf16_t* __restrict__ qh, const bf16_t* __restrict__ khg,
    int* __restrict__ fcand, int* __restrict__ fcnt) {
  __shared__ __align__(16) float  W8[8][64][8];   // 16384 B: per-wave top-8 group maxima
  __shared__ float Tarr[64];
  __shared__ int   cntq[64];
  __shared__ int   Cand[64][CAP];                 // 10240 B  (total ~27.4 KB)

  const int tid = threadIdx.x;
  const int lane = tid & 63, w = tid >> 6;        // 8 waves
  const int l15 = lane & 15, quad = lane >> 4;
  const int qbase = blockIdx.x * 64;
  const int split = blockIdx.y;
  const int key0 = split * (Mm / KSPLIT);
  constexpr int NT = (Mm / KSPLIT) / 128;         // 32 tiles of 128 keys

  bf16x8 bq[4][2];
#pragma unroll
  for (int g = 0; g < 4; ++g) {
    const bf16_t* qp = qh + (size_t)(qbase + g * 16 + l15) * HD + quad * 8;
    bq[g][0] = *(const bf16x8*)qp;
    bq[g][1] = *(const bf16x8*)(qp + 32);
  }

  // per-lane A-fragment source: key row (w*16 + l15) of each 128-key tile
  const bf16_t* kbase = khg + (size_t)(key0 + w * 16 + l15) * HD + quad * 8;

  float s8[8];
#pragma unroll
  for (int r = 0; r < 8; ++r) s8[r] = -3.0e38f;

  // ---- Pass 1: group maxima -> per-lane top-8 (no barriers) ----
  bf16x8 a0 = *(const bf16x8*)(kbase);
  bf16x8 a1 = *(const bf16x8*)(kbase + 32);
  for (int tile = 0; tile < NT; ++tile) {
    const bf16_t* np = kbase + (size_t)((tile + 1 < NT) ? tile + 1 : 0) * (128 * HD);
    bf16x8 n0 = *(const bf16x8*)(np);
    bf16x8 n1 = *(const bf16x8*)(np + 32);
    float keep = -3.0e38f;
#pragma unroll
    for (int g = 0; g < 4; ++g) {
      f32x4 acc = {0.f, 0.f, 0.f, 0.f};
      acc = MFMA16(a0, bq[g][0], acc, 0, 0, 0);
      acc = MFMA16(a1, bq[g][1], acc, 0, 0, 0);
      float v = fmaxf(fmaxf(acc[0], acc[1]), fmaxf(acc[2], acc[3]));
      v = fmaxf(v, __shfl_xor(v, 16));
      v = fmaxf(v, __shfl_xor(v, 32));
      if (g == quad) keep = v;
    }
    if (keep > s8[7]) {
      s8[7] = keep;
#pragma unroll
      for (int p = 7; p > 0; --p)
        if (s8[p] > s8[p - 1]) { float t = s8[p]; s8[p] = s8[p - 1]; s8[p - 1] = t; }
    }
    a0 = n0; a1 = n1;
  }
  {
    float* dst = &W8[w][quad * 16 + l15][0];
#pragma unroll
    for (int r = 0; r < 8; ++r) dst[r] = s8[r];
  }
  __syncthreads();
  if (tid < 64) {
    float t8[8];
#pragma unroll
    for (int r = 0; r < 8; ++r) t8[r] = -3.0e38f;
#pragma unroll
    for (int wv2 = 0; wv2 < 8; ++wv2) {
      float4 u0 = *(const float4*)&W8[wv2][tid][0];
      float4 u1 = *(const float4*)&W8[wv2][tid][4];
      float vals[8] = {u0.x, u0.y, u0.z, u0.w, u1.x, u1.y, u1.z, u1.w};
#pragma unroll
      for (int r = 0; r < 8; ++r) {
        float v = vals[r];
        if (v > t8[7]) {
          t8[7] = v;
#pragma unroll
          for (int p = 7; p > 0; --p)
            if (t8[p] > t8[p - 1]) { float tt = t8[p]; t8[p] = t8[p - 1]; t8[p - 1] = tt; }
        }
      }
    }
    Tarr[tid] = t8[7];
    cntq[tid] = 0;
  }
  __syncthreads();
  float Tq[4];
#pragma unroll
  for (int g = 0; g < 4; ++g) Tq[g] = Tarr[g * 16 + l15];

  // ---- Pass 2: bit-identical replay (same operands -> same scores), push survivors ----
  a0 = *(const bf16x8*)(kbase);
  a1 = *(const bf16x8*)(kbase + 32);
  for (int tile = 0; tile < NT; ++tile) {
    const bf16_t* np = kbase + (size_t)((tile + 1 < NT) ? tile + 1 : 0) * (128 * HD);
    bf16x8 n0 = *(const bf16x8*)(np);
    bf16x8 n1 = *(const bf16x8*)(np + 32);
#pragma unroll
    for (int g = 0; g < 4; ++g) {
      f32x4 acc = {0.f, 0.f, 0.f, 0.f};
      acc = MFMA16(a0, bq[g][0], acc, 0, 0, 0);
      acc = MFMA16(a1, bq[g][1], acc, 0, 0, 0);
      const int kb = key0 + tile * 128 + w * 16 + quad * 4;
      const int qq = g * 16 + l15;
#pragma unroll
      for (int r = 0; r < 4; ++r) {
        if (acc[r] >= Tq[g]) {
          int pos = atomicAdd(&cntq[qq], 1);
          if (pos < CAP) Cand[qq][pos] = kb + r;
        }
      }
    }
    a0 = n0; a1 = n1;
  }
  __syncthreads();
  if (tid < 64) {
    int c = cntq[tid];
    fcnt[(size_t)split * NQ + qbase + tid] = (c < CAP) ? c : CAP;
  }
  for (int i = tid; i < 64 * CAP; i += 512) {
    int q = i / CAP, s = i - q * CAP;
    fcand[((size_t)split * NQ + qbase + q) * CAP + s] = Cand[q][s];
  }
}

// ---------------- Kernel 3: exact f32 rescore of candidates -> top-8 ----------------
// grid NQ/64 blocks x 64 threads: one query per lane, all 256 CUs covered.
__global__ __launch_bounds__(64) void rescore8(
    const float* __restrict__ qf, const float* __restrict__ mk,
    const int* __restrict__ fcand, const int* __restrict__ fcnt,
    int* __restrict__ f8) {
  const int qid = blockIdx.x * 64 + threadIdx.x;
  float q[64];
#pragma unroll
  for (int c = 0; c < 16; ++c) {
    float4 v4 = *(const float4*)(qf + (size_t)qid * HD + 4 * c);
    q[4*c]=v4.x; q[4*c+1]=v4.y; q[4*c+2]=v4.z; q[4*c+3]=v4.w;
  }
  float sc[TK]; int id[TK];
#pragma unroll
  for (int r = 0; r < TK; ++r) { sc[r] = -3.0e38f; id[r] = 0x7fffffff; }
#pragma unroll 1
  for (int sp = 0; sp < KSPLIT; ++sp) {
    int cnt = fcnt[(size_t)sp * NQ + qid];
    if (cnt > CAP) cnt = CAP;
#pragma unroll 1
    for (int c = 0; c < cnt; ++c) {
      int kidx = fcand[((size_t)sp * NQ + qid) * CAP + c] & (Mm - 1);
      const float4* kr = (const float4*)(mk + (size_t)kidx * HD);
      float a0 = 0, a1 = 0, a2 = 0, a3 = 0;
#pragma unroll
      for (int cc = 0; cc < 16; ++cc) {
        float4 kv = kr[cc];
        a0 += q[4*cc]*kv.x; a1 += q[4*cc+1]*kv.y; a2 += q[4*cc+2]*kv.z; a3 += q[4*cc+3]*kv.w;
      }
      float s = (a0 + a1) + (a2 + a3);
      if (s > sc[TK - 1] || (s == sc[TK - 1] && kidx < id[TK - 1])) {
        sc[TK - 1] = s; id[TK - 1] = kidx;
#pragma unroll
        for (int p = TK - 1; p > 0; --p) {
          bool sw = (sc[p] > sc[p - 1]) || (sc[p] == sc[p - 1] && id[p] < id[p - 1]);
          if (sw) {
            float ts = sc[p]; sc[p] = sc[p - 1]; sc[p - 1] = ts;
            int   ti = id[p]; id[p] = id[p - 1]; id[p - 1] = ti;
          }
        }
      }
    }
  }
#pragma unroll
  for (int r = 0; r < TK; ++r) f8[(size_t)qid * TK + r] = id[r] & (Mm - 1);
}

// ---------------- Kernel 4: unified MFMA flash attention (mem gather + local causal) ----------------
// grid (8 qt, 32 bh, 4 chunk), block 256 (4 waves). 1024 blocks = 4/CU matching the
// LDS/VGPR residency cap. Local causal tiles on chunk 0 (dispatched first -> no tail).
// Chunk 3's O-accumulator aliases the free FCAND tail. P exchange fully in-register.
__global__ __launch_bounds__(256) void flash_mfma(
    const bf16_t* __restrict__ qh, const bf16_t* __restrict__ ql,
    const bf16_t* __restrict__ kh2, const bf16_t* __restrict__ kl2,
    const bf16_t* __restrict__ vh2, const bf16_t* __restrict__ vl2,
    const bf16_t* __restrict__ khg, const bf16_t* __restrict__ gkl,
    const bf16_t* __restrict__ gvh, const bf16_t* __restrict__ gvl,
    const int* __restrict__ f8, float* __restrict__ ml, float* __restrict__ pacc,
    float* __restrict__ pa3) {
  __shared__ __align__(16) bf16_t KH[64][72];    // 9216 B
  __shared__ __align__(16) bf16_t KL[64][72];    // 9216 B
  __shared__ __align__(16) bf16_t VTH[64][68];   // 8704 B: V^T hi bf16, stride 68
  __shared__ __align__(16) bf16_t VTL[64][68];   // 8704 B   (total 35840 -> 4 blocks/CU)

  const int tid = threadIdx.x;
  const int lane = tid & 63, w = tid >> 6;
  const int l15 = lane & 15, quad = lane >> 4;
  const int qt = blockIdx.x, bh = blockIdx.y, chunk = blockIdx.z;
  const int il = qt * 64 + w * 16 + l15;
  const int qid = bh * Ls + il;
  const bf16x8 qh0 = *(const bf16x8*)(qh + (size_t)qid * HD + quad * 8);
  const bf16x8 qh1 = *(const bf16x8*)(qh + (size_t)qid * HD + 32 + quad * 8);
  const bf16x8 ql0 = *(const bf16x8*)(ql + (size_t)qid * HD + quad * 8);
  const bf16x8 ql1 = *(const bf16x8*)(ql + (size_t)qid * HD + 32 + quad * 8);

  f32x4 O[4] = {};
  float m = -3.0e38f, lsum = 0.f;
  const float scale = 0.125f;
  const int tbase = chunk * 16;                       // mem tile base: 0/16/32/48
  constexpr int nmem = 16;                            // mem tiles per chunk
  const int ntiles = (chunk == 0) ? 17 + qt : 16;     // + local causal tiles on chunk 0
  const int skey = tid >> 2, spart = tid & 3;         // K staging: 1 key x 16 dims
  const int kpair = tid & 31, dgroup = tid >> 5;      // V staging: 2 keys x 8 dims

  bf16x8 kA0, kA1, kB0, kB1;        // K hi/lo fragments for staging
  bf16x8 vha, vhb, vla, vlb;        // raw V rows (2 keys x 8 dims, hi/lo)
  bf16x2 vth[8], vtl[8];            // packed transposed V pairs
  auto stage_load = [&](int t) {
    const bf16_t *ksh, *ksl, *vah, *val_, *vbh, *vbl;
    if (chunk == 0 && t >= nmem) {
      int jlK = (t - nmem) * 64 + skey;
      size_t ro = ((size_t)bh * Ls + jlK) * HD + spart * 16;
      ksh = kh2 + ro; ksl = kl2 + ro;
      int jlV = (t - nmem) * 64 + 2 * kpair;
      size_t ra = ((size_t)bh * Ls + jlV) * HD + dgroup * 8;
      vah = vh2 + ra;      val_ = vl2 + ra;
      vbh = vh2 + ra + HD; vbl  = vl2 + ra + HD;
    } else {
      int jgK = (tbase + t) * 64 + skey;
      int sK = f8[((size_t)bh * Ls + (jgK >> 3)) * TK + (jgK & 7)] & (Mm - 1);
      size_t ro = (size_t)sK * HD + spart * 16;
      ksh = khg + ro; ksl = gkl + ro;
      int jgV = (tbase + t) * 64 + 2 * kpair;          // even -> pair stays in one f8 row
      int2 s2 = *(const int2*)(f8 + ((size_t)bh * Ls + (jgV >> 3)) * TK + (jgV & 7));
      size_t ra = (size_t)(s2.x & (Mm - 1)) * HD + dgroup * 8;
      size_t rb = (size_t)(s2.y & (Mm - 1)) * HD + dgroup * 8;
      vah = gvh + ra; val_ = gvl + ra;
      vbh = gvh + rb; vbl  = gvl + rb;
    }
    kA0 = *(const bf16x8*)ksh; kA1 = *(const bf16x8*)(ksh + 8);
    kB0 = *(const bf16x8*)ksl; kB1 = *(const bf16x8*)(ksl + 8);
    vha = *(const bf16x8*)vah; vla = *(const bf16x8*)val_;
    vhb = *(const bf16x8*)vbh; vlb = *(const bf16x8*)vbl;
  };
  auto pack_v = [&]() {
#pragma unroll
    for (int j = 0; j < 8; ++j) {
      vth[j][0] = vha[j]; vth[j][1] = vhb[j];
      vtl[j][0] = vla[j]; vtl[j][1] = vlb[j];
    }
  };
  stage_load(0);
  pack_v();

  for (int tile = 0; tile < ntiles; ++tile) {
    const bool local_tile = (chunk == 0) && (tile >= nmem);
    __syncthreads();
    {
      *(bf16x8*)&KH[skey][spart * 16]     = kA0;
      *(bf16x8*)&KH[skey][spart * 16 + 8] = kA1;
      *(bf16x8*)&KL[skey][spart * 16]     = kB0;
      *(bf16x8*)&KL[skey][spart * 16 + 8] = kB1;
#pragma unroll
      for (int j = 0; j < 8; ++j) {
        *(bf16x2*)&VTH[dgroup * 8 + j][2 * kpair] = vth[j];
        *(bf16x2*)&VTL[dgroup * 8 + j][2 * kpair] = vtl[j];
      }
    }
    __syncthreads();
    if (tile + 1 < ntiles) stage_load(tile + 1);   // overlap next-tile HBM with compute

    f32x4 S[4];
    __builtin_amdgcn_s_setprio(1);
#pragma unroll
    for (int sub = 0; sub < 4; ++sub) {
      const bf16x8 ah0 = *(const bf16x8*)&KH[sub * 16 + l15][quad * 8];
      const bf16x8 ah1 = *(const bf16x8*)&KH[sub * 16 + l15][32 + quad * 8];
      const bf16x8 al0 = *(const bf16x8*)&KL[sub * 16 + l15][quad * 8];
      const bf16x8 al1 = *(const bf16x8*)&KL[sub * 16 + l15][32 + quad * 8];
      f32x4 acc = {0.f, 0.f, 0.f, 0.f};
      acc = MFMA16(ah0, qh0, acc, 0, 0, 0);
      acc = MFMA16(ah1, qh1, acc, 0, 0, 0);
      acc = MFMA16(al0, qh0, acc, 0, 0, 0);
      acc = MFMA16(al1, qh1, acc, 0, 0, 0);
      acc = MFMA16(ah0, ql0, acc, 0, 0, 0);
      acc = MFMA16(ah1, ql1, acc, 0, 0, 0);
#pragma unroll
      for (int r = 0; r < 4; ++r) {
        float sv = acc[r] * scale;
        if (local_tile && ((tile - nmem) * 64 + sub * 16 + quad * 4 + r) > il) sv = -3.0e38f;
        S[sub][r] = sv;
      }
    }
    __builtin_amdgcn_s_setprio(0);
    float tm = -3.0e38f;
#pragma unroll
    for (int sub = 0; sub < 4; ++sub)
#pragma unroll
      for (int r = 0; r < 4; ++r) tm = fmaxf(tm, S[sub][r]);
    tm = fmaxf(tm, __shfl_xor(tm, 16));
    tm = fmaxf(tm, __shfl_xor(tm, 32));
    float mnew = fmaxf(m, tm);
    float alpha = __expf(m - mnew);
    lsum *= alpha;
#pragma unroll
    for (int t = 0; t < 4; ++t) O[t] *= alpha;
    m = mnew;

    // P computation: pack each sub's 4 bf16 hi/lo into u64 registers (static indexing)
    unsigned long long ph64[4], pl64[4];
#pragma unroll
    for (int sub = 0; sub < 4; ++sub) {
      bf16_t ph4[4], pl4[4];
#pragma unroll
      for (int r = 0; r < 4; ++r) {
        float p = __expf(S[sub][r] - mnew);
        lsum += p;
        bf16_t hv = (bf16_t)p;
        ph4[r] = hv;
        pl4[r] = (bf16_t)(p - (float)hv);
      }
      unsigned long long th, tl;
      __builtin_memcpy(&th, ph4, 8);
      __builtin_memcpy(&tl, pl4, 8);
      ph64[sub] = th; pl64[sub] = tl;
    }
    // In-register exchange within the 4-lane column group (replaces PH/PL LDS):
    // target (l15,quad) needs keys quad*8..+7 (frag 0) and 32+quad*8..+7 (frag 1) of
    // query l15. Owners: oA=(quad&1)*2 (keys j=0..3), oB=oA+1 (j=4..7); subs slo=quad>>1,
    // shi=2+slo. Done hi-THEN-lo with reused temps: peak live shfl temps = 8 u64.
    const int srcA = ((quad & 1) << 5) + l15;   // lane of owner quad oA
    const int srcB = srcA + 16;                 // lane of owner quad oB
    const bool hsel = (quad & 2) != 0;          // slo = quad>>1
    bf16x8 ph0, ph1, pl0, pl1;
    {
      unsigned long long tA0 = __shfl(ph64[0], srcA), tA1 = __shfl(ph64[1], srcA);
      unsigned long long tA2 = __shfl(ph64[2], srcA), tA3 = __shfl(ph64[3], srcA);
      unsigned long long tB0 = __shfl(ph64[0], srcB), tB1 = __shfl(ph64[1], srcB);
      unsigned long long tB2 = __shfl(ph64[2], srcB), tB3 = __shfl(ph64[3], srcB);
      ph0 = cat8(hsel ? tA1 : tA0, hsel ? tB1 : tB0);
      ph1 = cat8(hsel ? tA3 : tA2, hsel ? tB3 : tB2);
    }
    {
      unsigned long long tA0 = __shfl(pl64[0], srcA), tA1 = __shfl(pl64[1], srcA);
      unsigned long long tA2 = __shfl(pl64[2], srcA), tA3 = __shfl(pl64[3], srcA);
      unsigned long long tB0 = __shfl(pl64[0], srcB), tB1 = __shfl(pl64[1], srcB);
      unsigned long long tB2 = __shfl(pl64[2], srcB), tB3 = __shfl(pl64[3], srcB);
      pl0 = cat8(hsel ? tA1 : tA0, hsel ? tB1 : tB0);
      pl1 = cat8(hsel ? tA3 : tA2, hsel ? tB3 : tB2);
    }

    __builtin_amdgcn_s_setprio(1);
#pragma unroll
    for (int t = 0; t < 4; ++t) {
      const bf16x8 vh0 = ld8h(&VTH[t * 16 + l15][quad * 8]);
      const bf16x8 vh1 = ld8h(&VTH[t * 16 + l15][32 + quad * 8]);
      const bf16x8 vl0 = ld8h(&VTL[t * 16 + l15][quad * 8]);
      const bf16x8 vl1 = ld8h(&VTL[t * 16 + l15][32 + quad * 8]);
      O[t] = MFMA16(vh0, ph0, O[t], 0, 0, 0);
      O[t] = MFMA16(vh1, ph1, O[t], 0, 0, 0);
      O[t] = MFMA16(vl0, ph0, O[t], 0, 0, 0);
      O[t] = MFMA16(vl1, ph1, O[t], 0, 0, 0);
      O[t] = MFMA16(vh0, pl0, O[t], 0, 0, 0);
      O[t] = MFMA16(vh1, pl1, O[t], 0, 0, 0);
    }
    __builtin_amdgcn_s_setprio(0);
    if (tile + 1 < ntiles) pack_v();               // pack next V after loads have landed
  }
  lsum += __shfl_xor(lsum, 16);
  lsum += __shfl_xor(lsum, 32);
  if (quad == 0) {
    ml[((size_t)chunk * NQ + qid) * 2 + 0] = m;
    ml[((size_t)chunk * NQ + qid) * 2 + 1] = lsum;
  }
  float* pa = (chunk == 3) ? (pa3 + (size_t)qid * 64)
                           : (pacc + ((size_t)chunk * NQ + qid) * 64);
#pragma unroll
  for (int t = 0; t < 4; ++t) {
    float4 v4; v4.x = O[t][0]; v4.y = O[t][1]; v4.z = O[t][2]; v4.w = O[t][3];
    *(float4*)(pa + t * 16 + quad * 4) = v4;
  }
}

// ---------------- Kernel 5: O-projection, fused 4-way LSE combine, W-tile LDS staged ----------------
__global__ __launch_bounds__(256) void oproj_comb(
    const float* __restrict__ ml, const float* __restrict__ pacc,
    const float* __restrict__ pa3,
    const float* __restrict__ Wo, const float* __restrict__ bo,
    float* __restrict__ out) {
  __shared__ __align__(16) bf16_t WHs[2][64][40];
  __shared__ __align__(16) bf16_t WLs[2][64][40];
  const int tid = threadIdx.x;
  const int lane = tid & 63, wv = tid >> 6;
  const int l15 = lane & 15, quad = lane >> 4;
  const int mrow = blockIdx.x * 64 + wv * 16 + l15;    // token row 0..1023
  const int b = mrow >> 9, l = mrow & 511;
  const int ncol0 = blockIdx.y * 64;
  const int srow = tid >> 2, scol = (tid & 3) * 8;
  const size_t wbase = (size_t)(ncol0 + srow) * Dd + scol;
  f32x4 acc[4] = {};
  {
    float wv8[8]; ld8f(Wo + wbase, wv8);
    bf16x8 h, l2; split8(wv8, h, l2);
    *(bf16x8*)&WHs[0][srow][scol] = h;
    *(bf16x8*)&WLs[0][srow][scol] = l2;
  }
  int p = 0;
  for (int kk = 0; kk < Dd; kk += 32) {
    __syncthreads();
    if (kk + 32 < Dd) {
      float wv8[8]; ld8f(Wo + wbase + kk + 32, wv8);
      bf16x8 h, l2; split8(wv8, h, l2);
      *(bf16x8*)&WHs[p ^ 1][srow][scol] = h;
      *(bf16x8*)&WLs[p ^ 1][srow][scol] = l2;
    }
    const int h = kk >> 6;
    const size_t qid = (size_t)(b * Hh + h) * Ls + l;
    float m0 = ml[qid * 2 + 0],                    l0 = ml[qid * 2 + 1];
    float m1 = ml[((size_t)NQ + qid) * 2 + 0],     l1 = ml[((size_t)NQ + qid) * 2 + 1];
    float m2 = ml[((size_t)2 * NQ + qid) * 2 + 0], l2v = ml[((size_t)2 * NQ + qid) * 2 + 1];
    float m3 = ml[((size_t)3 * NQ + qid) * 2 + 0], l3v = ml[((size_t)3 * NQ + qid) * 2 + 1];
    float M = fmaxf(fmaxf(m0, m1), fmaxf(m2, m3));
    float w0 = __expf(m0 - M), w1 = __expf(m1 - M), w2 = __expf(m2 - M), w3 = __expf(m3 - M);
    float inv = 1.f / (w0 * l0 + w1 * l1 + w2 * l2v + w3 * l3v);
    const int d0 = (kk & 63) + quad * 8;
    float a0v[8], a1v[8], a2v[8], a3v[8], av[8];
    ld8f(pacc + qid * 64 + d0, a0v);
    ld8f(pacc + ((size_t)NQ + qid) * 64 + d0, a1v);
    ld8f(pacc + ((size_t)2 * NQ + qid) * 64 + d0, a2v);
    ld8f(pa3 + qid * 64 + d0, a3v);
#pragma unroll
    for (int j = 0; j < 8; ++j)
      av[j] = (w0 * a0v[j] + w1 * a1v[j] + w2 * a2v[j] + w3 * a3v[j]) * inv;
    bf16x8 ahi, alo; split8(av, ahi, alo);
#pragma unroll
    for (int t = 0; t < 4; ++t) {
      const bf16x8 whi = *(const bf16x8*)&WHs[p][t * 16 + l15][quad * 8];
      const bf16x8 wlo = *(const bf16x8*)&WLs[p][t * 16 + l15][quad * 8];
      acc[t] = MFMA16(ahi, whi, acc[t], 0, 0, 0);
      acc[t] = MFMA16(alo, whi, acc[t], 0, 0, 0);
      acc[t] = MFMA16(ahi, wlo, acc[t], 0, 0, 0);
    }
    p ^= 1;
  }
#pragma unroll
  for (int t = 0; t < 4; ++t) {
    int col = ncol0 + t * 16 + l15;
    float bb = bo[col];
#pragma unroll
    for (int r = 0; r < 4; ++r) {
      int row = blockIdx.x * 64 + wv * 16 + quad * 4 + r;
      out[(size_t)row * Dd + col] = acc[t][r] + bb;
    }
  }
}

extern "C" void kernel_launch(void* const* d_in, const int* in_sizes, int n_in,
                              void* d_out, int out_size, void* d_ws, size_t ws_size,
                              hipStream_t stream) {
  (void)in_sizes; (void)n_in;
  const float* x  = (const float*)d_in[0];
  const float* mk = (const float*)d_in[1];
  const float* mv = (const float*)d_in[2];
  const float* Wq = (const float*)d_in[3];
  const float* bq = (const float*)d_in[4];
  const float* Wk = (const float*)d_in[5];
  const float* bk = (const float*)d_in[6];
  const float* Wv = (const float*)d_in[7];
  const float* bv = (const float*)d_in[8];
  const float* Wo = (const float*)d_in[9];
  const float* bo = (const float*)d_in[10];
  float* ws = (float*)d_ws;

  if (ws_size < WS_BYTES) {   // constant per-problem -> graph-safe
    float v = (float)(ws_size >> 20) + 0.5f;
    ws_sentinel<<<(out_size + 255) / 256, 256, 0, stream>>>((float*)d_out, out_size, v);
    return;
  }

  float*  QF    = ws + OFF_QF;
  bf16_t* KH2   = (bf16_t*)(ws + OFF_KH2);
  bf16_t* KL2   = (bf16_t*)(ws + OFF_KL2);
  bf16_t* VH2   = (bf16_t*)(ws + OFF_VH2);
  bf16_t* VL2   = (bf16_t*)(ws + OFF_VL2);
  bf16_t* QH    = (bf16_t*)(ws + OFF_QH);
  bf16_t* QL    = (bf16_t*)(ws + OFF_QL);
  bf16_t* KHG   = (bf16_t*)(ws + OFF_KHG);
  int*    FCAND = (int*)(ws + OFF_FCAND);
  int*    FCNT  = (int*)(ws + OFF_FCNT);
  int*    F8    = (int*)(ws + OFF_F8);
  float*  ML    = ws + OFF_ML;
  float*  PA    = ws + OFF_PA;
  bf16_t* GKL   = (bf16_t*)(ws + OFF_GKL);
  bf16_t* GVH   = (bf16_t*)(ws + OFF_GVH);
  bf16_t* GVL   = (bf16_t*)(ws + OFF_GVL);
  float*  PA3   = ws + OFF_PA3;

  prep_keys<<<(Mm * HD) / (256 * 8), 256, 0, stream>>>(mk, KHG);
  qkv_mfma<<<dim3(16, 16, 3), 256, 0, stream>>>(x, Wq, bq, Wk, bk, Wv, bv,
                                                QF, QH, QL, KH2, KL2, VH2, VL2);
  topk_thresh<<<dim3(NQ / 64, KSPLIT), 512, 0, stream>>>(QH, KHG, FCAND, FCNT);
  rescore8<<<NQ / 64, 64, 0, stream>>>(QF, mk, FCAND, FCNT, F8);
  prep_kv2<<<(Mm * HD) / (256 * 8), 256, 0, stream>>>(mk, mv, GKL, GVH, GVL);
  flash_mfma<<<dim3(8, 32, 4), 256, 0, stream>>>(QH, QL, KH2, KL2, VH2, VL2,
                                                 KHG, GKL, GVH, GVL, F8, ML, PA, PA3);
  oproj_comb<<<dim3(16, 16), 256, 0, stream>>>(ML, PA, PA3, Wo, bo, (float*)d_out);
}

// Round 13
// 481.966 us; speedup vs baseline: 1.0905x; 1.0905x over previous
//
#include <hip/hip_runtime.h>

typedef __bf16 bf16_t;
typedef __bf16 bf16x8 __attribute__((ext_vector_type(8)));
typedef __bf16 bf16x4 __attribute__((ext_vector_type(4)));
typedef __bf16 bf16x2 __attribute__((ext_vector_type(2)));
typedef float f32x4 __attribute__((ext_vector_type(4)));

#define DEV __device__ __forceinline__
#define MFMA16 __builtin_amdgcn_mfma_f32_16x16x32_bf16

constexpr int Bb = 2, Ls = 512, Dd = 1024, Hh = 16, HD = 64, Mm = 16384, TK = 8;
constexpr int KSPLIT = 4;          // key splits for topk occupancy
constexpr int CAP = 40;            // candidate buffer per (query, split); E[count]~9
constexpr int NQ = Bb * Ls * Hh;   // 16384 query-heads; bh-major qid = (b*16+h)*512 + l
constexpr int CH = 4;              // attention chunks: mem 16x4 tiles; local causal on chunk 0

// f32-unit workspace layout (~43.3 MB; >=47.3 MB known available)
constexpr size_t OFF_QF   = 0;                                    // Q f32 [NQ][64]
constexpr size_t OFF_KH2  = OFF_QF + (size_t)NQ * HD;             // K hi bf16 [NQ][64]
constexpr size_t OFF_KL2  = OFF_KH2 + (size_t)NQ * HD / 2;        // K lo bf16
constexpr size_t OFF_VH2  = OFF_KL2 + (size_t)NQ * HD / 2;        // V hi bf16
constexpr size_t OFF_VL2  = OFF_VH2 + (size_t)NQ * HD / 2;        // V lo bf16
constexpr size_t OFF_QH   = OFF_VL2 + (size_t)NQ * HD / 2;        // Q hi bf16 [NQ][64]
constexpr size_t OFF_QL   = OFF_QH + (size_t)NQ * HD / 2;         // Q lo bf16
constexpr size_t OFF_KHG  = OFF_QL + (size_t)NQ * HD / 2;         // mem keys hi bf16 [M][64]
constexpr size_t OFF_FCAND = OFF_KHG + (size_t)Mm * HD / 2;       // int [KSPLIT][NQ][CAP]
constexpr size_t OFF_FCNT  = OFF_FCAND + (size_t)KSPLIT * NQ * CAP; // int [KSPLIT][NQ]
constexpr size_t OFF_F8   = OFF_FCNT + (size_t)KSPLIT * NQ;       // int [NQ][8]
constexpr size_t OFF_ML   = OFF_F8 + (size_t)NQ * TK;             // (m,l) [CH][NQ][2]
constexpr size_t OFF_PA   = OFF_ML + (size_t)CH * NQ * 2;         // acc [3][NQ][64] (chunk 3 aliased)
constexpr size_t WS_ELEMS = OFF_PA + (size_t)3 * NQ * HD + 16;
constexpr size_t WS_BYTES = WS_ELEMS * 4;

// aliases into FCAND region (dead after rescore8; written by prep_kv2 / flash)
constexpr size_t OFF_GKL = OFF_FCAND;                             // mem keys lo bf16 [M][64]
constexpr size_t OFF_GVH = OFF_GKL + (size_t)Mm * HD / 2;         // mem vals hi bf16
constexpr size_t OFF_GVL = OFF_GVH + (size_t)Mm * HD / 2;         // mem vals lo bf16
constexpr size_t OFF_PA3 = OFF_GVL + (size_t)Mm * HD / 2;         // acc chunk 3 [NQ][64] f32
static_assert(OFF_PA3 + (size_t)NQ * HD <= OFF_FCNT, "PA3 alias fits in FCAND");

DEV void ld8f(const float* p, float* dst) {
  float4 a = *(const float4*)p, b = *(const float4*)(p + 4);
  dst[0]=a.x; dst[1]=a.y; dst[2]=a.z; dst[3]=a.w;
  dst[4]=b.x; dst[5]=b.y; dst[6]=b.z; dst[7]=b.w;
}

DEV void split8(const float* av, bf16x8& hi, bf16x8& lo) {
#pragma unroll
  for (int j = 0; j < 8; ++j) {
    bf16_t h_ = (bf16_t)av[j];
    hi[j] = h_;
    lo[j] = (bf16_t)(av[j] - (float)h_);
  }
}

// 8B-aligned bf16x8 load (rows of stride-68 bf16 arrays are 8B- but not 16B-aligned)
DEV bf16x8 ld8h(const bf16_t* p) {
  bf16x4 a = *(const bf16x4*)p;
  bf16x4 b = *(const bf16x4*)(p + 4);
  bf16x8 r;
#pragma unroll
  for (int i = 0; i < 4; ++i) { r[i] = a[i]; r[i + 4] = b[i]; }
  return r;
}

// concat two 4xbf16 (as u64) into a bf16x8 MFMA fragment
DEV bf16x8 cat8(unsigned long long lo, unsigned long long hi) {
  bf16x8 r;
  __builtin_memcpy(&r, &lo, 8);
  __builtin_memcpy(reinterpret_cast<char*>(&r) + 8, &hi, 8);
  return r;
}

__global__ __launch_bounds__(256) void ws_sentinel(float* __restrict__ out, int n, float v) {
  int i = blockIdx.x * 256 + threadIdx.x;
  if (i < n) out[i] = v;
}

// ---------------- Kernel 0: pre-convert memory keys to bf16 hi (once) ----------------
__global__ __launch_bounds__(256) void prep_keys(const float* __restrict__ mk,
                                                 bf16_t* __restrict__ khg) {
  const size_t i = ((size_t)blockIdx.x * 256 + threadIdx.x) * 8;
  float v[8]; ld8f(mk + i, v);
  bf16x8 h;
#pragma unroll
  for (int j = 0; j < 8; ++j) h[j] = (bf16_t)v[j];
  *(bf16x8*)(khg + i) = h;
}

// ---------------- Kernel 0b: pre-split mem keys lo + mem values hi/lo (after rescore8) ----------------
__global__ __launch_bounds__(256) void prep_kv2(const float* __restrict__ mk,
                                                const float* __restrict__ mv,
                                                bf16_t* __restrict__ gkl,
                                                bf16_t* __restrict__ gvh,
                                                bf16_t* __restrict__ gvl) {
  const size_t i = ((size_t)blockIdx.x * 256 + threadIdx.x) * 8;
  float a[8]; ld8f(mk + i, a);
  float b[8]; ld8f(mv + i, b);
  bf16x8 kl, vh, vl;
#pragma unroll
  for (int j = 0; j < 8; ++j) {
    bf16_t kh_ = (bf16_t)a[j];
    kl[j] = (bf16_t)(a[j] - (float)kh_);
    bf16_t vh_ = (bf16_t)b[j];
    vh[j] = vh_;
    vl[j] = (bf16_t)(b[j] - (float)vh_);
  }
  *(bf16x8*)(gkl + i) = kl;
  *(bf16x8*)(gvh + i) = vh;
  *(bf16x8*)(gvl + i) = vl;
}

// ---------------- Kernel 1: QKV projection, W-tile LDS staged, 3-term split MFMA ----------------
__global__ __launch_bounds__(256) void qkv_mfma(
    const float* __restrict__ x,
    const float* __restrict__ Wq, const float* __restrict__ bq,
    const float* __restrict__ Wk, const float* __restrict__ bk,
    const float* __restrict__ Wv, const float* __restrict__ bv,
    float* __restrict__ qf, bf16_t* __restrict__ qhp, bf16_t* __restrict__ qlp,
    bf16_t* __restrict__ kh2, bf16_t* __restrict__ kl2,
    bf16_t* __restrict__ vh2, bf16_t* __restrict__ vl2) {
  __shared__ __align__(16) bf16_t WHs[2][64][40];   // 10240 B
  __shared__ __align__(16) bf16_t WLs[2][64][40];   // 10240 B
  const int z = blockIdx.z;
  const float* W    = (z == 0) ? Wq : ((z == 1) ? Wk : Wv);
  const float* bias = (z == 0) ? bq : ((z == 1) ? bk : bv);
  const int tid = threadIdx.x;
  const int lane = tid & 63, wv = tid >> 6;
  const int l15 = lane & 15, quad = lane >> 4;
  const int mrow = blockIdx.x * 64 + wv * 16 + l15;
  const int ncol0 = blockIdx.y * 64;
  const int srow = tid >> 2, scol = (tid & 3) * 8;  // staging: 64 rows x 32 k, 8 f32/thread
  f32x4 acc[4] = {};
  const size_t abase = (size_t)mrow * Dd + quad * 8;
  const size_t wbase = (size_t)(ncol0 + srow) * Dd + scol;
  {
    float wv8[8]; ld8f(W + wbase, wv8);
    bf16x8 h, l; split8(wv8, h, l);
    *(bf16x8*)&WHs[0][srow][scol] = h;
    *(bf16x8*)&WLs[0][srow][scol] = l;
  }
  int p = 0;
  for (int kk = 0; kk < Dd; kk += 32) {
    __syncthreads();
    if (kk + 32 < Dd) {
      float wv8[8]; ld8f(W + wbase + kk + 32, wv8);
      bf16x8 h, l; split8(wv8, h, l);
      *(bf16x8*)&WHs[p ^ 1][srow][scol] = h;
      *(bf16x8*)&WLs[p ^ 1][srow][scol] = l;
    }
    float av[8]; ld8f(x + abase + kk, av);
    bf16x8 ahi, alo; split8(av, ahi, alo);
#pragma unroll
    for (int t = 0; t < 4; ++t) {
      const bf16x8 bhi = *(const bf16x8*)&WHs[p][t * 16 + l15][quad * 8];
      const bf16x8 blo = *(const bf16x8*)&WLs[p][t * 16 + l15][quad * 8];
      acc[t] = MFMA16(ahi, bhi, acc[t], 0, 0, 0);
      acc[t] = MFMA16(alo, bhi, acc[t], 0, 0, 0);
      acc[t] = MFMA16(ahi, blo, acc[t], 0, 0, 0);
    }
    p ^= 1;
  }
#pragma unroll
  for (int t = 0; t < 4; ++t) {
    int col = ncol0 + t * 16 + l15;
    int h = col >> 6, hd = col & 63;
    float bb = bias[col];
#pragma unroll
    for (int r = 0; r < 4; ++r) {
      int row = blockIdx.x * 64 + wv * 16 + quad * 4 + r;   // token row = b*512+l
      int b = row >> 9, l = row & 511;
      float val = acc[t][r] + bb;
      size_t o = ((size_t)(b * Hh + h) * Ls + l) * HD + hd;
      if (z == 0) {
        qf[o] = val;
        bf16_t hv = (bf16_t)val;
        qhp[o] = hv;
        qlp[o] = (bf16_t)(val - (float)hv);
      } else {
        bf16_t hv = (bf16_t)val;
        bf16_t lv = (bf16_t)(val - (float)hv);
        if (z == 1) { kh2[o] = hv; kl2[o] = lv; }
        else        { vh2[o] = hv; vl2[o] = lv; }
      }
    }
  }
}

// ---------------- Kernel 2: threshold-filter coarse top-k, barrier-free direct loads ----------------
// The measured local optimum (137.8 us in the R11 pipeline): direct global->VGPR
// A-fragments, no LDS staging, no per-tile barriers; passes replay bit-identically.
// Five restructures (2-half grid, 4-key groups, 32x32, dual-chain prefetch, 8-wave
// blocks) all regressed or washed; occupancy is pinned ~44% regardless of config.
__global__ __launch_bounds__(256, 5) void topk_thresh(
    const bf16_t* __restrict__ qh, const bf16_t* __restrict__ khg,
    int* __restrict__ fcand, int* __restrict__ fcnt) {
  __shared__ __align__(16) float  W8[4][64][8];   // 8192 B: per-wave top-8 group maxima
  __shared__ float Tarr[64];
  __shared__ int   cntq[64];
  __shared__ int   Cand[64][CAP];                 // 10240 B

  const int tid = threadIdx.x;
  const int lane = tid & 63, w = tid >> 6;
  const int l15 = lane & 15, quad = lane >> 4;
  const int qbase = blockIdx.x * 64;
  const int split = blockIdx.y;
  const int key0 = split * (Mm / KSPLIT);
  constexpr int NT = (Mm / KSPLIT) / 64;          // 64 tiles of 64 keys

  bf16x8 bq[4][2];
#pragma unroll
  for (int g = 0; g < 4; ++g) {
    const bf16_t* qp = qh + (size_t)(qbase + g * 16 + l15) * HD + quad * 8;
    bq[g][0] = *(const bf16x8*)qp;
    bq[g][1] = *(const bf16x8*)(qp + 32);
  }

  // per-lane A-fragment source: key row (w*16 + l15) of each tile, dims quad*8 / 32+quad*8
  const bf16_t* kbase = khg + (size_t)(key0 + w * 16 + l15) * HD + quad * 8;

  float s8[8];
#pragma unroll
  for (int r = 0; r < 8; ++r) s8[r] = -3.0e38f;

  // ---- Pass 1: group maxima -> per-lane top-8 (no barriers) ----
  bf16x8 a0 = *(const bf16x8*)(kbase);
  bf16x8 a1 = *(const bf16x8*)(kbase + 32);
  for (int tile = 0; tile < NT; ++tile) {
    const bf16_t* np = kbase + (size_t)((tile + 1 < NT) ? tile + 1 : 0) * (64 * HD);
    bf16x8 n0 = *(const bf16x8*)(np);
    bf16x8 n1 = *(const bf16x8*)(np + 32);
    float keep = -3.0e38f;
#pragma unroll
    for (int g = 0; g < 4; ++g) {
      f32x4 acc = {0.f, 0.f, 0.f, 0.f};
      acc = MFMA16(a0, bq[g][0], acc, 0, 0, 0);
      acc = MFMA16(a1, bq[g][1], acc, 0, 0, 0);
      float v = fmaxf(fmaxf(acc[0], acc[1]), fmaxf(acc[2], acc[3]));
      v = fmaxf(v, __shfl_xor(v, 16));
      v = fmaxf(v, __shfl_xor(v, 32));
      if (g == quad) keep = v;
    }
    if (keep > s8[7]) {
      s8[7] = keep;
#pragma unroll
      for (int p = 7; p > 0; --p)
        if (s8[p] > s8[p - 1]) { float t = s8[p]; s8[p] = s8[p - 1]; s8[p - 1] = t; }
    }
    a0 = n0; a1 = n1;
  }
  {
    float* dst = &W8[w][quad * 16 + l15][0];
#pragma unroll
    for (int r = 0; r < 8; ++r) dst[r] = s8[r];
  }
  __syncthreads();
  if (tid < 64) {
    float t8[8];
#pragma unroll
    for (int r = 0; r < 8; ++r) t8[r] = -3.0e38f;
#pragma unroll
    for (int wv2 = 0; wv2 < 4; ++wv2) {
      float4 u0 = *(const float4*)&W8[wv2][tid][0];
      float4 u1 = *(const float4*)&W8[wv2][tid][4];
      float vals[8] = {u0.x, u0.y, u0.z, u0.w, u1.x, u1.y, u1.z, u1.w};
#pragma unroll
      for (int r = 0; r < 8; ++r) {
        float v = vals[r];
        if (v > t8[7]) {
          t8[7] = v;
#pragma unroll
          for (int p = 7; p > 0; --p)
            if (t8[p] > t8[p - 1]) { float tt = t8[p]; t8[p] = t8[p - 1]; t8[p - 1] = tt; }
        }
      }
    }
    Tarr[tid] = t8[7];
    cntq[tid] = 0;
  }
  __syncthreads();
  float Tq[4];
#pragma unroll
  for (int g = 0; g < 4; ++g) Tq[g] = Tarr[g * 16 + l15];

  // ---- Pass 2: bit-identical replay (same operands -> same scores), push survivors ----
  a0 = *(const bf16x8*)(kbase);
  a1 = *(const bf16x8*)(kbase + 32);
  for (int tile = 0; tile < NT; ++tile) {
    const bf16_t* np = kbase + (size_t)((tile + 1 < NT) ? tile + 1 : 0) * (64 * HD);
    bf16x8 n0 = *(const bf16x8*)(np);
    bf16x8 n1 = *(const bf16x8*)(np + 32);
#pragma unroll
    for (int g = 0; g < 4; ++g) {
      f32x4 acc = {0.f, 0.f, 0.f, 0.f};
      acc = MFMA16(a0, bq[g][0], acc, 0, 0, 0);
      acc = MFMA16(a1, bq[g][1], acc, 0, 0, 0);
      const int kb = key0 + tile * 64 + w * 16 + quad * 4;
      const int qq = g * 16 + l15;
#pragma unroll
      for (int r = 0; r < 4; ++r) {
        if (acc[r] >= Tq[g]) {
          int pos = atomicAdd(&cntq[qq], 1);
          if (pos < CAP) Cand[qq][pos] = kb + r;
        }
      }
    }
    a0 = n0; a1 = n1;
  }
  __syncthreads();
  if (tid < 64) {
    int c = cntq[tid];
    fcnt[(size_t)split * NQ + qbase + tid] = (c < CAP) ? c : CAP;
  }
  for (int i = tid; i < 64 * CAP; i += 256) {
    int q = i / CAP, s = i - q * CAP;
    fcand[((size_t)split * NQ + qbase + q) * CAP + s] = Cand[q][s];
  }
}

// ---------------- Kernel 3: exact f32 rescore of candidates -> top-8, split-parallel ----------------
// grid NQ/64 blocks x 256 threads (4 waves). The old 64-thread form ran ONE wave per CU --
// zero latency hiding for a chain of dependent L2 gathers. Now thread (ql, sp=tid>>6)
// scans only split sp's candidates (the split loop was already independent), keeping a
// per-split top-8 under the same (score desc, id asc) total order; the 4 sorted lists
// merge through LDS with the identical comparator -> bit-identical union-top-8.
__global__ __launch_bounds__(256) void rescore8(
    const float* __restrict__ qf, const float* __restrict__ mk,
    const int* __restrict__ fcand, const int* __restrict__ fcnt,
    int* __restrict__ f8) {
  __shared__ float Ssc[64][4][8];   // 8192 B
  __shared__ int   Sid[64][4][8];   // 8192 B
  const int tid = threadIdx.x;
  const int ql = tid & 63, sp = tid >> 6;
  const int qid = blockIdx.x * 64 + ql;
  float q[64];
#pragma unroll
  for (int c = 0; c < 16; ++c) {
    float4 v4 = *(const float4*)(qf + (size_t)qid * HD + 4 * c);
    q[4*c]=v4.x; q[4*c+1]=v4.y; q[4*c+2]=v4.z; q[4*c+3]=v4.w;
  }
  float sc[TK]; int id[TK];
#pragma unroll
  for (int r = 0; r < TK; ++r) { sc[r] = -3.0e38f; id[r] = 0x7fffffff; }
  int cnt = fcnt[(size_t)sp * NQ + qid];
  if (cnt > CAP) cnt = CAP;
#pragma unroll 1
  for (int c = 0; c < cnt; ++c) {
    int kidx = fcand[((size_t)sp * NQ + qid) * CAP + c] & (Mm - 1);
    const float4* kr = (const float4*)(mk + (size_t)kidx * HD);
    float a0 = 0, a1 = 0, a2 = 0, a3 = 0;
#pragma unroll
    for (int cc = 0; cc < 16; ++cc) {
      float4 kv = kr[cc];
      a0 += q[4*cc]*kv.x; a1 += q[4*cc+1]*kv.y; a2 += q[4*cc+2]*kv.z; a3 += q[4*cc+3]*kv.w;
    }
    float s = (a0 + a1) + (a2 + a3);
    if (s > sc[TK - 1] || (s == sc[TK - 1] && kidx < id[TK - 1])) {
      sc[TK - 1] = s; id[TK - 1] = kidx;
#pragma unroll
      for (int p = TK - 1; p > 0; --p) {
        bool sw = (sc[p] > sc[p - 1]) || (sc[p] == sc[p - 1] && id[p] < id[p - 1]);
        if (sw) {
          float ts = sc[p]; sc[p] = sc[p - 1]; sc[p - 1] = ts;
          int   ti = id[p]; id[p] = id[p - 1]; id[p - 1] = ti;
        }
      }
    }
  }
#pragma unroll
  for (int r = 0; r < TK; ++r) { Ssc[ql][sp][r] = sc[r]; Sid[ql][sp][r] = id[r]; }
  __syncthreads();
  if (tid < 64) {
    float mc[TK]; int mi[TK];
#pragma unroll
    for (int r = 0; r < TK; ++r) { mc[r] = -3.0e38f; mi[r] = 0x7fffffff; }
#pragma unroll
    for (int s2 = 0; s2 < 4; ++s2) {
#pragma unroll
      for (int r = 0; r < TK; ++r) {
        float v = Ssc[tid][s2][r];
        int  vi = Sid[tid][s2][r];
        if (v > mc[TK - 1] || (v == mc[TK - 1] && vi < mi[TK - 1])) {
          mc[TK - 1] = v; mi[TK - 1] = vi;
#pragma unroll
          for (int p = TK - 1; p > 0; --p) {
            bool sw = (mc[p] > mc[p - 1]) || (mc[p] == mc[p - 1] && mi[p] < mi[p - 1]);
            if (sw) {
              float ts = mc[p]; mc[p] = mc[p - 1]; mc[p - 1] = ts;
              int   ti = mi[p]; mi[p] = mi[p - 1]; mi[p - 1] = ti;
            }
          }
        }
      }
    }
    const int qo = blockIdx.x * 64 + tid;
#pragma unroll
    for (int r = 0; r < TK; ++r) f8[(size_t)qo * TK + r] = mi[r] & (Mm - 1);
  }
}

// ---------------- Kernel 4: unified MFMA flash attention (mem gather + local causal) ----------------
// grid (8 qt, 32 bh, 4 chunk), block 256 (4 waves). 1024 blocks = 4/CU matching the
// LDS/VGPR residency cap. Local causal tiles on chunk 0 (dispatched first -> no tail).
// Chunk 3's O-accumulator aliases the free FCAND tail. P exchange fully in-register.
__global__ __launch_bounds__(256) void flash_mfma(
    const bf16_t* __restrict__ qh, const bf16_t* __restrict__ ql,
    const bf16_t* __restrict__ kh2, const bf16_t* __restrict__ kl2,
    const bf16_t* __restrict__ vh2, const bf16_t* __restrict__ vl2,
    const bf16_t* __restrict__ khg, const bf16_t* __restrict__ gkl,
    const bf16_t* __restrict__ gvh, const bf16_t* __restrict__ gvl,
    const int* __restrict__ f8, float* __restrict__ ml, float* __restrict__ pacc,
    float* __restrict__ pa3) {
  __shared__ __align__(16) bf16_t KH[64][72];    // 9216 B
  __shared__ __align__(16) bf16_t KL[64][72];    // 9216 B
  __shared__ __align__(16) bf16_t VTH[64][68];   // 8704 B: V^T hi bf16, stride 68
  __shared__ __align__(16) bf16_t VTL[64][68];   // 8704 B   (total 35840 -> 4 blocks/CU)

  const int tid = threadIdx.x;
  const int lane = tid & 63, w = tid >> 6;
  const int l15 = lane & 15, quad = lane >> 4;
  const int qt = blockIdx.x, bh = blockIdx.y, chunk = blockIdx.z;
  const int il = qt * 64 + w * 16 + l15;
  const int qid = bh * Ls + il;
  const bf16x8 qh0 = *(const bf16x8*)(qh + (size_t)qid * HD + quad * 8);
  const bf16x8 qh1 = *(const bf16x8*)(qh + (size_t)qid * HD + 32 + quad * 8);
  const bf16x8 ql0 = *(const bf16x8*)(ql + (size_t)qid * HD + quad * 8);
  const bf16x8 ql1 = *(const bf16x8*)(ql + (size_t)qid * HD + 32 + quad * 8);

  f32x4 O[4] = {};
  float m = -3.0e38f, lsum = 0.f;
  const float scale = 0.125f;
  const int tbase = chunk * 16;                       // mem tile base: 0/16/32/48
  constexpr int nmem = 16;                            // mem tiles per chunk
  const int ntiles = (chunk == 0) ? 17 + qt : 16;     // + local causal tiles on chunk 0
  const int skey = tid >> 2, spart = tid & 3;         // K staging: 1 key x 16 dims
  const int kpair = tid & 31, dgroup = tid >> 5;      // V staging: 2 keys x 8 dims

  bf16x8 kA0, kA1, kB0, kB1;        // K hi/lo fragments for staging
  bf16x8 vha, vhb, vla, vlb;        // raw V rows (2 keys x 8 dims, hi/lo)
  bf16x2 vth[8], vtl[8];            // packed transposed V pairs
  auto stage_load = [&](int t) {
    const bf16_t *ksh, *ksl, *vah, *val_, *vbh, *vbl;
    if (chunk == 0 && t >= nmem) {
      int jlK = (t - nmem) * 64 + skey;
      size_t ro = ((size_t)bh * Ls + jlK) * HD + spart * 16;
      ksh = kh2 + ro; ksl = kl2 + ro;
      int jlV = (t - nmem) * 64 + 2 * kpair;
      size_t ra = ((size_t)bh * Ls + jlV) * HD + dgroup * 8;
      vah = vh2 + ra;      val_ = vl2 + ra;
      vbh = vh2 + ra + HD; vbl  = vl2 + ra + HD;
    } else {
      int jgK = (tbase + t) * 64 + skey;
      int sK = f8[((size_t)bh * Ls + (jgK >> 3)) * TK + (jgK & 7)] & (Mm - 1);
      size_t ro = (size_t)sK * HD + spart * 16;
      ksh = khg + ro; ksl = gkl + ro;
      int jgV = (tbase + t) * 64 + 2 * kpair;          // even -> pair stays in one f8 row
      int2 s2 = *(const int2*)(f8 + ((size_t)bh * Ls + (jgV >> 3)) * TK + (jgV & 7));
      size_t ra = (size_t)(s2.x & (Mm - 1)) * HD + dgroup * 8;
      size_t rb = (size_t)(s2.y & (Mm - 1)) * HD + dgroup * 8;
      vah = gvh + ra; val_ = gvl + ra;
      vbh = gvh + rb; vbl  = gvl + rb;
    }
    kA0 = *(const bf16x8*)ksh; kA1 = *(const bf16x8*)(ksh + 8);
    kB0 = *(const bf16x8*)ksl; kB1 = *(const bf16x8*)(ksl + 8);
    vha = *(const bf16x8*)vah; vla = *(const bf16x8*)val_;
    vhb = *(const bf16x8*)vbh; vlb = *(const bf16x8*)vbl;
  };
  auto pack_v = [&]() {
#pragma unroll
    for (int j = 0; j < 8; ++j) {
      vth[j][0] = vha[j]; vth[j][1] = vhb[j];
      vtl[j][0] = vla[j]; vtl[j][1] = vlb[j];
    }
  };
  stage_load(0);
  pack_v();

  for (int tile = 0; tile < ntiles; ++tile) {
    const bool local_tile = (chunk == 0) && (tile >= nmem);
    __syncthreads();
    {
      *(bf16x8*)&KH[skey][spart * 16]     = kA0;
      *(bf16x8*)&KH[skey][spart * 16 + 8] = kA1;
      *(bf16x8*)&KL[skey][spart * 16]     = kB0;
      *(bf16x8*)&KL[skey][spart * 16 + 8] = kB1;
#pragma unroll
      for (int j = 0; j < 8; ++j) {
        *(bf16x2*)&VTH[dgroup * 8 + j][2 * kpair] = vth[j];
        *(bf16x2*)&VTL[dgroup * 8 + j][2 * kpair] = vtl[j];
      }
    }
    __syncthreads();
    if (tile + 1 < ntiles) stage_load(tile + 1);   // overlap next-tile HBM with compute

    f32x4 S[4];
    __builtin_amdgcn_s_setprio(1);
#pragma unroll
    for (int sub = 0; sub < 4; ++sub) {
      const bf16x8 ah0 = *(const bf16x8*)&KH[sub * 16 + l15][quad * 8];
      const bf16x8 ah1 = *(const bf16x8*)&KH[sub * 16 + l15][32 + quad * 8];
      const bf16x8 al0 = *(const bf16x8*)&KL[sub * 16 + l15][quad * 8];
      const bf16x8 al1 = *(const bf16x8*)&KL[sub * 16 + l15][32 + quad * 8];
      f32x4 acc = {0.f, 0.f, 0.f, 0.f};
      acc = MFMA16(ah0, qh0, acc, 0, 0, 0);
      acc = MFMA16(ah1, qh1, acc, 0, 0, 0);
      acc = MFMA16(al0, qh0, acc, 0, 0, 0);
      acc = MFMA16(al1, qh1, acc, 0, 0, 0);
      acc = MFMA16(ah0, ql0, acc, 0, 0, 0);
      acc = MFMA16(ah1, ql1, acc, 0, 0, 0);
#pragma unroll
      for (int r = 0; r < 4; ++r) {
        float sv = acc[r] * scale;
        if (local_tile && ((tile - nmem) * 64 + sub * 16 + quad * 4 + r) > il) sv = -3.0e38f;
        S[sub][r] = sv;
      }
    }
    __builtin_amdgcn_s_setprio(0);
    float tm = -3.0e38f;
#pragma unroll
    for (int sub = 0; sub < 4; ++sub)
#pragma unroll
      for (int r = 0; r < 4; ++r) tm = fmaxf(tm, S[sub][r]);
    tm = fmaxf(tm, __shfl_xor(tm, 16));
    tm = fmaxf(tm, __shfl_xor(tm, 32));
    float mnew = fmaxf(m, tm);
    float alpha = __expf(m - mnew);
    lsum *= alpha;
#pragma unroll
    for (int t = 0; t < 4; ++t) O[t] *= alpha;
    m = mnew;

    // P computation: pack each sub's 4 bf16 hi/lo into u64 registers (static indexing)
    unsigned long long ph64[4], pl64[4];
#pragma unroll
    for (int sub = 0; sub < 4; ++sub) {
      bf16_t ph4[4], pl4[4];
#pragma unroll
      for (int r = 0; r < 4; ++r) {
        float p = __expf(S[sub][r] - mnew);
        lsum += p;
        bf16_t hv = (bf16_t)p;
        ph4[r] = hv;
        pl4[r] = (bf16_t)(p - (float)hv);
      }
      unsigned long long th, tl;
      __builtin_memcpy(&th, ph4, 8);
      __builtin_memcpy(&tl, pl4, 8);
      ph64[sub] = th; pl64[sub] = tl;
    }
    // In-register exchange within the 4-lane column group (replaces PH/PL LDS):
    // target (l15,quad) needs keys quad*8..+7 (frag 0) and 32+quad*8..+7 (frag 1) of
    // query l15. Owners: oA=(quad&1)*2 (keys j=0..3), oB=oA+1 (j=4..7); subs slo=quad>>1,
    // shi=2+slo. Done hi-THEN-lo with reused temps: peak live shfl temps = 8 u64.
    const int srcA = ((quad & 1) << 5) + l15;   // lane of owner quad oA
    const int srcB = srcA + 16;                 // lane of owner quad oB
    const bool hsel = (quad & 2) != 0;          // slo = quad>>1
    bf16x8 ph0, ph1, pl0, pl1;
    {
      unsigned long long tA0 = __shfl(ph64[0], srcA), tA1 = __shfl(ph64[1], srcA);
      unsigned long long tA2 = __shfl(ph64[2], srcA), tA3 = __shfl(ph64[3], srcA);
      unsigned long long tB0 = __shfl(ph64[0], srcB), tB1 = __shfl(ph64[1], srcB);
      unsigned long long tB2 = __shfl(ph64[2], srcB), tB3 = __shfl(ph64[3], srcB);
      ph0 = cat8(hsel ? tA1 : tA0, hsel ? tB1 : tB0);
      ph1 = cat8(hsel ? tA3 : tA2, hsel ? tB3 : tB2);
    }
    {
      unsigned long long tA0 = __shfl(pl64[0], srcA), tA1 = __shfl(pl64[1], srcA);
      unsigned long long tA2 = __shfl(pl64[2], srcA), tA3 = __shfl(pl64[3], srcA);
      unsigned long long tB0 = __shfl(pl64[0], srcB), tB1 = __shfl(pl64[1], srcB);
      unsigned long long tB2 = __shfl(pl64[2], srcB), tB3 = __shfl(pl64[3], srcB);
      pl0 = cat8(hsel ? tA1 : tA0, hsel ? tB1 : tB0);
      pl1 = cat8(hsel ? tA3 : tA2, hsel ? tB3 : tB2);
    }

    __builtin_amdgcn_s_setprio(1);
#pragma unroll
    for (int t = 0; t < 4; ++t) {
      const bf16x8 vh0 = ld8h(&VTH[t * 16 + l15][quad * 8]);
      const bf16x8 vh1 = ld8h(&VTH[t * 16 + l15][32 + quad * 8]);
      const bf16x8 vl0 = ld8h(&VTL[t * 16 + l15][quad * 8]);
      const bf16x8 vl1 = ld8h(&VTL[t * 16 + l15][32 + quad * 8]);
      O[t] = MFMA16(vh0, ph0, O[t], 0, 0, 0);
      O[t] = MFMA16(vh1, ph1, O[t], 0, 0, 0);
      O[t] = MFMA16(vl0, ph0, O[t], 0, 0, 0);
      O[t] = MFMA16(vl1, ph1, O[t], 0, 0, 0);
      O[t] = MFMA16(vh0, pl0, O[t], 0, 0, 0);
      O[t] = MFMA16(vh1, pl1, O[t], 0, 0, 0);
    }
    __builtin_amdgcn_s_setprio(0);
    if (tile + 1 < ntiles) pack_v();               // pack next V after loads have landed
  }
  lsum += __shfl_xor(lsum, 16);
  lsum += __shfl_xor(lsum, 32);
  if (quad == 0) {
    ml[((size_t)chunk * NQ + qid) * 2 + 0] = m;
    ml[((size_t)chunk * NQ + qid) * 2 + 1] = lsum;
  }
  float* pa = (chunk == 3) ? (pa3 + (size_t)qid * 64)
                           : (pacc + ((size_t)chunk * NQ + qid) * 64);
#pragma unroll
  for (int t = 0; t < 4; ++t) {
    float4 v4; v4.x = O[t][0]; v4.y = O[t][1]; v4.z = O[t][2]; v4.w = O[t][3];
    *(float4*)(pa + t * 16 + quad * 4) = v4;
  }
}

// ---------------- Kernel 5: O-projection, fused 4-way LSE combine, W-tile LDS staged ----------------
__global__ __launch_bounds__(256) void oproj_comb(
    const float* __restrict__ ml, const float* __restrict__ pacc,
    const float* __restrict__ pa3,
    const float* __restrict__ Wo, const float* __restrict__ bo,
    float* __restrict__ out) {
  __shared__ __align__(16) bf16_t WHs[2][64][40];
  __shared__ __align__(16) bf16_t WLs[2][64][40];
  const int tid = threadIdx.x;
  const int lane = tid & 63, wv = tid >> 6;
  const int l15 = lane & 15, quad = lane >> 4;
  const int mrow = blockIdx.x * 64 + wv * 16 + l15;    // token row 0..1023
  const int b = mrow >> 9, l = mrow & 511;
  const int ncol0 = blockIdx.y * 64;
  const int srow = tid >> 2, scol = (tid & 3) * 8;
  const size_t wbase = (size_t)(ncol0 + srow) * Dd + scol;
  f32x4 acc[4] = {};
  {
    float wv8[8]; ld8f(Wo + wbase, wv8);
    bf16x8 h, l2; split8(wv8, h, l2);
    *(bf16x8*)&WHs[0][srow][scol] = h;
    *(bf16x8*)&WLs[0][srow][scol] = l2;
  }
  int p = 0;
  for (int kk = 0; kk < Dd; kk += 32) {
    __syncthreads();
    if (kk + 32 < Dd) {
      float wv8[8]; ld8f(Wo + wbase + kk + 32, wv8);
      bf16x8 h, l2; split8(wv8, h, l2);
      *(bf16x8*)&WHs[p ^ 1][srow][scol] = h;
      *(bf16x8*)&WLs[p ^ 1][srow][scol] = l2;
    }
    const int h = kk >> 6;
    const size_t qid = (size_t)(b * Hh + h) * Ls + l;
    float m0 = ml[qid * 2 + 0],                    l0 = ml[qid * 2 + 1];
    float m1 = ml[((size_t)NQ + qid) * 2 + 0],     l1 = ml[((size_t)NQ + qid) * 2 + 1];
    float m2 = ml[((size_t)2 * NQ + qid) * 2 + 0], l2v = ml[((size_t)2 * NQ + qid) * 2 + 1];
    float m3 = ml[((size_t)3 * NQ + qid) * 2 + 0], l3v = ml[((size_t)3 * NQ + qid) * 2 + 1];
    float M = fmaxf(fmaxf(m0, m1), fmaxf(m2, m3));
    float w0 = __expf(m0 - M), w1 = __expf(m1 - M), w2 = __expf(m2 - M), w3 = __expf(m3 - M);
    float inv = 1.f / (w0 * l0 + w1 * l1 + w2 * l2v + w3 * l3v);
    const int d0 = (kk & 63) + quad * 8;
    float a0v[8], a1v[8], a2v[8], a3v[8], av[8];
    ld8f(pacc + qid * 64 + d0, a0v);
    ld8f(pacc + ((size_t)NQ + qid) * 64 + d0, a1v);
    ld8f(pacc + ((size_t)2 * NQ + qid) * 64 + d0, a2v);
    ld8f(pa3 + qid * 64 + d0, a3v);
#pragma unroll
    for (int j = 0; j < 8; ++j)
      av[j] = (w0 * a0v[j] + w1 * a1v[j] + w2 * a2v[j] + w3 * a3v[j]) * inv;
    bf16x8 ahi, alo; split8(av, ahi, alo);
#pragma unroll
    for (int t = 0; t < 4; ++t) {
      const bf16x8 whi = *(const bf16x8*)&WHs[p][t * 16 + l15][quad * 8];
      const bf16x8 wlo = *(const bf16x8*)&WLs[p][t * 16 + l15][quad * 8];
      acc[t] = MFMA16(ahi, whi, acc[t], 0, 0, 0);
      acc[t] = MFMA16(alo, whi, acc[t], 0, 0, 0);
      acc[t] = MFMA16(ahi, wlo, acc[t], 0, 0, 0);
    }
    p ^= 1;
  }
#pragma unroll
  for (int t = 0; t < 4; ++t) {
    int col = ncol0 + t * 16 + l15;
    float bb = bo[col];
#pragma unroll
    for (int r = 0; r < 4; ++r) {
      int row = blockIdx.x * 64 + wv * 16 + quad * 4 + r;
      out[(size_t)row * Dd + col] = acc[t][r] + bb;
    }
  }
}

extern "C" void kernel_launch(void* const* d_in, const int* in_sizes, int n_in,
                              void* d_out, int out_size, void* d_ws, size_t ws_size,
                              hipStream_t stream) {
  (void)in_sizes; (void)n_in;
  const float* x  = (const float*)d_in[0];
  const float* mk = (const float*)d_in[1];
  const float* mv = (const float*)d_in[2];
  const float* Wq = (const float*)d_in[3];
  const float* bq = (const float*)d_in[4];
  const float* Wk = (const float*)d_in[5];
  const float* bk = (const float*)d_in[6];
  const float* Wv = (const float*)d_in[7];
  const float* bv = (const float*)d_in[8];
  const float* Wo = (const float*)d_in[9];
  const float* bo = (const float*)d_in[10];
  float* ws = (float*)d_ws;

  if (ws_size < WS_BYTES) {   // constant per-problem -> graph-safe
    float v = (float)(ws_size >> 20) + 0.5f;
    ws_sentinel<<<(out_size + 255) / 256, 256, 0, stream>>>((float*)d_out, out_size, v);
    return;
  }

  float*  QF    = ws + OFF_QF;
  bf16_t* KH2   = (bf16_t*)(ws + OFF_KH2);
  bf16_t* KL2   = (bf16_t*)(ws + OFF_KL2);
  bf16_t* VH2   = (bf16_t*)(ws + OFF_VH2);
  bf16_t* VL2   = (bf16_t*)(ws + OFF_VL2);
  bf16_t* QH    = (bf16_t*)(ws + OFF_QH);
  bf16_t* QL    = (bf16_t*)(ws + OFF_QL);
  bf16_t* KHG   = (bf16_t*)(ws + OFF_KHG);
  int*    FCAND = (int*)(ws + OFF_FCAND);
  int*    FCNT  = (int*)(ws + OFF_FCNT);
  int*    F8    = (int*)(ws + OFF_F8);
  float*  ML    = ws + OFF_ML;
  float*  PA    = ws + OFF_PA;
  bf16_t* GKL   = (bf16_t*)(ws + OFF_GKL);
  bf16_t* GVH   = (bf16_t*)(ws + OFF_GVH);
  bf16_t* GVL   = (bf16_t*)(ws + OFF_GVL);
  float*  PA3   = ws + OFF_PA3;

  prep_keys<<<(Mm * HD) / (256 * 8), 256, 0, stream>>>(mk, KHG);
  qkv_mfma<<<dim3(16, 16, 3), 256, 0, stream>>>(x, Wq, bq, Wk, bk, Wv, bv,
                                                QF, QH, QL, KH2, KL2, VH2, VL2);
  topk_thresh<<<dim3(NQ / 64, KSPLIT), 256, 0, stream>>>(QH, KHG, FCAND, FCNT);
  rescore8<<<NQ / 64, 256, 0, stream>>>(QF, mk, FCAND, FCNT, F8);
  prep_kv2<<<(Mm * HD) / (256 * 8), 256, 0, stream>>>(mk, mv, GKL, GVH, GVL);
  flash_mfma<<<dim3(8, 32, 4), 256, 0, stream>>>(QH, QL, KH2, KL2, VH2, VL2,
                                                 KHG, GKL, GVH, GVL, F8, ML, PA, PA3);
  oproj_comb<<<dim3(16, 16), 256, 0, stream>>>(ML, PA, PA3, Wo, bo, (float*)d_out);
}

// Round 14
// 479.875 us; speedup vs baseline: 1.0953x; 1.0044x over previous
//
#include <hip/hip_runtime.h>

typedef __bf16 bf16_t;
typedef __bf16 bf16x8 __attribute__((ext_vector_type(8)));
typedef __bf16 bf16x4 __attribute__((ext_vector_type(4)));
typedef __bf16 bf16x2 __attribute__((ext_vector_type(2)));
typedef float f32x4 __attribute__((ext_vector_type(4)));

#define DEV __device__ __forceinline__
#define MFMA16 __builtin_amdgcn_mfma_f32_16x16x32_bf16

constexpr int Bb = 2, Ls = 512, Dd = 1024, Hh = 16, HD = 64, Mm = 16384, TK = 8;
constexpr int KSPLIT = 4;          // key splits for topk occupancy
constexpr int CAP = 40;            // candidate buffer per (query, split); E[count]~9
constexpr int NQ = Bb * Ls * Hh;   // 16384 query-heads; bh-major qid = (b*16+h)*512 + l
constexpr int CH = 4;              // attention chunks: mem 16x4 tiles; local causal on chunk 0

// f32-unit workspace layout (~45.8 MB; >=47.3 MB known available)
constexpr size_t OFF_QF   = 0;                                    // Q f32 [NQ][64]
constexpr size_t OFF_KH2  = OFF_QF + (size_t)NQ * HD;             // K hi bf16 [NQ][64]
constexpr size_t OFF_KL2  = OFF_KH2 + (size_t)NQ * HD / 2;        // K lo bf16
constexpr size_t OFF_VH2  = OFF_KL2 + (size_t)NQ * HD / 2;        // V hi bf16
constexpr size_t OFF_VL2  = OFF_VH2 + (size_t)NQ * HD / 2;        // V lo bf16
constexpr size_t OFF_QH   = OFF_VL2 + (size_t)NQ * HD / 2;        // Q hi bf16 [NQ][64]
constexpr size_t OFF_QL   = OFF_QH + (size_t)NQ * HD / 2;         // Q lo bf16
constexpr size_t OFF_KHG  = OFF_QL + (size_t)NQ * HD / 2;         // mem keys hi bf16 [M][64]
constexpr size_t OFF_FCAND = OFF_KHG + (size_t)Mm * HD / 2;       // int [KSPLIT][NQ][CAP]
constexpr size_t OFF_FCNT  = OFF_FCAND + (size_t)KSPLIT * NQ * CAP; // int [KSPLIT][NQ]
constexpr size_t OFF_F8   = OFF_FCNT + (size_t)KSPLIT * NQ;       // int [NQ][8]
constexpr size_t OFF_ML   = OFF_F8 + (size_t)NQ * TK;             // (m,l) [CH][NQ][2]
constexpr size_t OFF_PA   = OFF_ML + (size_t)CH * NQ * 2;         // acc [3][NQ][64] (chunk 3 aliased)
constexpr size_t OFF_XH   = OFF_PA + (size_t)3 * NQ * HD;         // x hi bf16 [1024][1024]
constexpr size_t OFF_XL   = OFF_XH + (size_t)Bb * Ls * Dd / 2;    // x lo bf16
constexpr size_t WS_ELEMS = OFF_XL + (size_t)Bb * Ls * Dd / 2 + 16;
constexpr size_t WS_BYTES = WS_ELEMS * 4;

// aliases into FCAND region (dead after rescore8; written by prep_kv2 / flash)
constexpr size_t OFF_GKL = OFF_FCAND;                             // mem keys lo bf16 [M][64]
constexpr size_t OFF_GVH = OFF_GKL + (size_t)Mm * HD / 2;         // mem vals hi bf16
constexpr size_t OFF_GVL = OFF_GVH + (size_t)Mm * HD / 2;         // mem vals lo bf16
constexpr size_t OFF_PA3 = OFF_GVL + (size_t)Mm * HD / 2;         // acc chunk 3 [NQ][64] f32
static_assert(OFF_PA3 + (size_t)NQ * HD <= OFF_FCNT, "PA3 alias fits in FCAND");

DEV void ld8f(const float* p, float* dst) {
  float4 a = *(const float4*)p, b = *(const float4*)(p + 4);
  dst[0]=a.x; dst[1]=a.y; dst[2]=a.z; dst[3]=a.w;
  dst[4]=b.x; dst[5]=b.y; dst[6]=b.z; dst[7]=b.w;
}

DEV void split8(const float* av, bf16x8& hi, bf16x8& lo) {
#pragma unroll
  for (int j = 0; j < 8; ++j) {
    bf16_t h_ = (bf16_t)av[j];
    hi[j] = h_;
    lo[j] = (bf16_t)(av[j] - (float)h_);
  }
}

// 8B-aligned bf16x8 load (rows of stride-68 bf16 arrays are 8B- but not 16B-aligned)
DEV bf16x8 ld8h(const bf16_t* p) {
  bf16x4 a = *(const bf16x4*)p;
  bf16x4 b = *(const bf16x4*)(p + 4);
  bf16x8 r;
#pragma unroll
  for (int i = 0; i < 4; ++i) { r[i] = a[i]; r[i + 4] = b[i]; }
  return r;
}

// concat two 4xbf16 (as u64) into a bf16x8 MFMA fragment
DEV bf16x8 cat8(unsigned long long lo, unsigned long long hi) {
  bf16x8 r;
  __builtin_memcpy(&r, &lo, 8);
  __builtin_memcpy(reinterpret_cast<char*>(&r) + 8, &hi, 8);
  return r;
}

__global__ __launch_bounds__(256) void ws_sentinel(float* __restrict__ out, int n, float v) {
  int i = blockIdx.x * 256 + threadIdx.x;
  if (i < n) out[i] = v;
}

// ---------------- Kernel 0: pre-convert memory keys to bf16 hi (once) ----------------
__global__ __launch_bounds__(256) void prep_keys(const float* __restrict__ mk,
                                                 bf16_t* __restrict__ khg) {
  const size_t i = ((size_t)blockIdx.x * 256 + threadIdx.x) * 8;
  float v[8]; ld8f(mk + i, v);
  bf16x8 h;
#pragma unroll
  for (int j = 0; j < 8; ++j) h[j] = (bf16_t)v[j];
  *(bf16x8*)(khg + i) = h;
}

// ---------------- Kernel 0a: pre-split x into bf16 hi/lo (once) ----------------
// qkv previously re-ran split8 on the same x fragments in EVERY kk step of EVERY
// (by,z) panel: 48x redundant conversion of the whole x matrix. Same rounding here
// -> bit-identical qkv output.
__global__ __launch_bounds__(256) void prep_x(const float* __restrict__ x,
                                              bf16_t* __restrict__ xh,
                                              bf16_t* __restrict__ xl) {
  const size_t i = ((size_t)blockIdx.x * 256 + threadIdx.x) * 8;
  float v[8]; ld8f(x + i, v);
  bf16x8 h, l;
  split8(v, h, l);
  *(bf16x8*)(xh + i) = h;
  *(bf16x8*)(xl + i) = l;
}

// ---------------- Kernel 0b: pre-split mem keys lo + mem values hi/lo (after rescore8) ----------------
__global__ __launch_bounds__(256) void prep_kv2(const float* __restrict__ mk,
                                                const float* __restrict__ mv,
                                                bf16_t* __restrict__ gkl,
                                                bf16_t* __restrict__ gvh,
                                                bf16_t* __restrict__ gvl) {
  const size_t i = ((size_t)blockIdx.x * 256 + threadIdx.x) * 8;
  float a[8]; ld8f(mk + i, a);
  float b[8]; ld8f(mv + i, b);
  bf16x8 kl, vh, vl;
#pragma unroll
  for (int j = 0; j < 8; ++j) {
    bf16_t kh_ = (bf16_t)a[j];
    kl[j] = (bf16_t)(a[j] - (float)kh_);
    bf16_t vh_ = (bf16_t)b[j];
    vh[j] = vh_;
    vl[j] = (bf16_t)(b[j] - (float)vh_);
  }
  *(bf16x8*)(gkl + i) = kl;
  *(bf16x8*)(gvh + i) = vh;
  *(bf16x8*)(gvl + i) = vl;
}

// ---------------- Kernel 1: QKV projection, W-tile LDS staged, pre-split x ----------------
__global__ __launch_bounds__(256) void qkv_mfma(
    const bf16_t* __restrict__ xh, const bf16_t* __restrict__ xl,
    const float* __restrict__ Wq, const float* __restrict__ bq,
    const float* __restrict__ Wk, const float* __restrict__ bk,
    const float* __restrict__ Wv, const float* __restrict__ bv,
    float* __restrict__ qf, bf16_t* __restrict__ qhp, bf16_t* __restrict__ qlp,
    bf16_t* __restrict__ kh2, bf16_t* __restrict__ kl2,
    bf16_t* __restrict__ vh2, bf16_t* __restrict__ vl2) {
  __shared__ __align__(16) bf16_t WHs[2][64][40];   // 10240 B
  __shared__ __align__(16) bf16_t WLs[2][64][40];   // 10240 B
  const int z = blockIdx.z;
  const float* W    = (z == 0) ? Wq : ((z == 1) ? Wk : Wv);
  const float* bias = (z == 0) ? bq : ((z == 1) ? bk : bv);
  const int tid = threadIdx.x;
  const int lane = tid & 63, wv = tid >> 6;
  const int l15 = lane & 15, quad = lane >> 4;
  const int mrow = blockIdx.x * 64 + wv * 16 + l15;
  const int ncol0 = blockIdx.y * 64;
  const int srow = tid >> 2, scol = (tid & 3) * 8;  // staging: 64 rows x 32 k, 8 f32/thread
  f32x4 acc[4] = {};
  const size_t abase = (size_t)mrow * Dd + quad * 8;
  const size_t wbase = (size_t)(ncol0 + srow) * Dd + scol;
  {
    float wv8[8]; ld8f(W + wbase, wv8);
    bf16x8 h, l; split8(wv8, h, l);
    *(bf16x8*)&WHs[0][srow][scol] = h;
    *(bf16x8*)&WLs[0][srow][scol] = l;
  }
  int p = 0;
  for (int kk = 0; kk < Dd; kk += 32) {
    __syncthreads();
    if (kk + 32 < Dd) {
      float wv8[8]; ld8f(W + wbase + kk + 32, wv8);
      bf16x8 h, l; split8(wv8, h, l);
      *(bf16x8*)&WHs[p ^ 1][srow][scol] = h;
      *(bf16x8*)&WLs[p ^ 1][srow][scol] = l;
    }
    const bf16x8 ahi = *(const bf16x8*)(xh + abase + kk);
    const bf16x8 alo = *(const bf16x8*)(xl + abase + kk);
#pragma unroll
    for (int t = 0; t < 4; ++t) {
      const bf16x8 bhi = *(const bf16x8*)&WHs[p][t * 16 + l15][quad * 8];
      const bf16x8 blo = *(const bf16x8*)&WLs[p][t * 16 + l15][quad * 8];
      acc[t] = MFMA16(ahi, bhi, acc[t], 0, 0, 0);
      acc[t] = MFMA16(alo, bhi, acc[t], 0, 0, 0);
      acc[t] = MFMA16(ahi, blo, acc[t], 0, 0, 0);
    }
    p ^= 1;
  }
#pragma unroll
  for (int t = 0; t < 4; ++t) {
    int col = ncol0 + t * 16 + l15;
    int h = col >> 6, hd = col & 63;
    float bb = bias[col];
#pragma unroll
    for (int r = 0; r < 4; ++r) {
      int row = blockIdx.x * 64 + wv * 16 + quad * 4 + r;   // token row = b*512+l
      int b = row >> 9, l = row & 511;
      float val = acc[t][r] + bb;
      size_t o = ((size_t)(b * Hh + h) * Ls + l) * HD + hd;
      if (z == 0) {
        qf[o] = val;
        bf16_t hv = (bf16_t)val;
        qhp[o] = hv;
        qlp[o] = (bf16_t)(val - (float)hv);
      } else {
        bf16_t hv = (bf16_t)val;
        bf16_t lv = (bf16_t)(val - (float)hv);
        if (z == 1) { kh2[o] = hv; kl2[o] = lv; }
        else        { vh2[o] = hv; vl2[o] = lv; }
      }
    }
  }
}

// ---------------- Kernel 2: threshold-filter coarse top-k, barrier-free direct loads ----------------
// The measured local optimum (137.8 us in the R11 pipeline): direct global->VGPR
// A-fragments, no LDS staging, no per-tile barriers; passes replay bit-identically.
// Five restructures (2-half grid, 4-key groups, 32x32, dual-chain prefetch, 8-wave
// blocks) all regressed or washed; occupancy is pinned ~44% regardless of config.
__global__ __launch_bounds__(256, 5) void topk_thresh(
    const bf16_t* __restrict__ qh, const bf16_t* __restrict__ khg,
    int* __restrict__ fcand, int* __restrict__ fcnt) {
  __shared__ __align__(16) float  W8[4][64][8];   // 8192 B: per-wave top-8 group maxima
  __shared__ float Tarr[64];
  __shared__ int   cntq[64];
  __shared__ int   Cand[64][CAP];                 // 10240 B

  const int tid = threadIdx.x;
  const int lane = tid & 63, w = tid >> 6;
  const int l15 = lane & 15, quad = lane >> 4;
  const int qbase = blockIdx.x * 64;
  const int split = blockIdx.y;
  const int key0 = split * (Mm / KSPLIT);
  constexpr int NT = (Mm / KSPLIT) / 64;          // 64 tiles of 64 keys

  bf16x8 bq[4][2];
#pragma unroll
  for (int g = 0; g < 4; ++g) {
    const bf16_t* qp = qh + (size_t)(qbase + g * 16 + l15) * HD + quad * 8;
    bq[g][0] = *(const bf16x8*)qp;
    bq[g][1] = *(const bf16x8*)(qp + 32);
  }

  // per-lane A-fragment source: key row (w*16 + l15) of each tile, dims quad*8 / 32+quad*8
  const bf16_t* kbase = khg + (size_t)(key0 + w * 16 + l15) * HD + quad * 8;

  float s8[8];
#pragma unroll
  for (int r = 0; r < 8; ++r) s8[r] = -3.0e38f;

  // ---- Pass 1: group maxima -> per-lane top-8 (no barriers) ----
  bf16x8 a0 = *(const bf16x8*)(kbase);
  bf16x8 a1 = *(const bf16x8*)(kbase + 32);
  for (int tile = 0; tile < NT; ++tile) {
    const bf16_t* np = kbase + (size_t)((tile + 1 < NT) ? tile + 1 : 0) * (64 * HD);
    bf16x8 n0 = *(const bf16x8*)(np);
    bf16x8 n1 = *(const bf16x8*)(np + 32);
    float keep = -3.0e38f;
#pragma unroll
    for (int g = 0; g < 4; ++g) {
      f32x4 acc = {0.f, 0.f, 0.f, 0.f};
      acc = MFMA16(a0, bq[g][0], acc, 0, 0, 0);
      acc = MFMA16(a1, bq[g][1], acc, 0, 0, 0);
      float v = fmaxf(fmaxf(acc[0], acc[1]), fmaxf(acc[2], acc[3]));
      v = fmaxf(v, __shfl_xor(v, 16));
      v = fmaxf(v, __shfl_xor(v, 32));
      if (g == quad) keep = v;
    }
    if (keep > s8[7]) {
      s8[7] = keep;
#pragma unroll
      for (int p = 7; p > 0; --p)
        if (s8[p] > s8[p - 1]) { float t = s8[p]; s8[p] = s8[p - 1]; s8[p - 1] = t; }
    }
    a0 = n0; a1 = n1;
  }
  {
    float* dst = &W8[w][quad * 16 + l15][0];
#pragma unroll
    for (int r = 0; r < 8; ++r) dst[r] = s8[r];
  }
  __syncthreads();
  if (tid < 64) {
    float t8[8];
#pragma unroll
    for (int r = 0; r < 8; ++r) t8[r] = -3.0e38f;
#pragma unroll
    for (int wv2 = 0; wv2 < 4; ++wv2) {
      float4 u0 = *(const float4*)&W8[wv2][tid][0];
      float4 u1 = *(const float4*)&W8[wv2][tid][4];
      float vals[8] = {u0.x, u0.y, u0.z, u0.w, u1.x, u1.y, u1.z, u1.w};
#pragma unroll
      for (int r = 0; r < 8; ++r) {
        float v = vals[r];
        if (v > t8[7]) {
          t8[7] = v;
#pragma unroll
          for (int p = 7; p > 0; --p)
            if (t8[p] > t8[p - 1]) { float tt = t8[p]; t8[p] = t8[p - 1]; t8[p - 1] = tt; }
        }
      }
    }
    Tarr[tid] = t8[7];
    cntq[tid] = 0;
  }
  __syncthreads();
  float Tq[4];
#pragma unroll
  for (int g = 0; g < 4; ++g) Tq[g] = Tarr[g * 16 + l15];

  // ---- Pass 2: bit-identical replay (same operands -> same scores), push survivors ----
  a0 = *(const bf16x8*)(kbase);
  a1 = *(const bf16x8*)(kbase + 32);
  for (int tile = 0; tile < NT; ++tile) {
    const bf16_t* np = kbase + (size_t)((tile + 1 < NT) ? tile + 1 : 0) * (64 * HD);
    bf16x8 n0 = *(const bf16x8*)(np);
    bf16x8 n1 = *(const bf16x8*)(np + 32);
#pragma unroll
    for (int g = 0; g < 4; ++g) {
      f32x4 acc = {0.f, 0.f, 0.f, 0.f};
      acc = MFMA16(a0, bq[g][0], acc, 0, 0, 0);
      acc = MFMA16(a1, bq[g][1], acc, 0, 0, 0);
      const int kb = key0 + tile * 64 + w * 16 + quad * 4;
      const int qq = g * 16 + l15;
#pragma unroll
      for (int r = 0; r < 4; ++r) {
        if (acc[r] >= Tq[g]) {
          int pos = atomicAdd(&cntq[qq], 1);
          if (pos < CAP) Cand[qq][pos] = kb + r;
        }
      }
    }
    a0 = n0; a1 = n1;
  }
  __syncthreads();
  if (tid < 64) {
    int c = cntq[tid];
    fcnt[(size_t)split * NQ + qbase + tid] = (c < CAP) ? c : CAP;
  }
  for (int i = tid; i < 64 * CAP; i += 256) {
    int q = i / CAP, s = i - q * CAP;
    fcand[((size_t)split * NQ + qbase + q) * CAP + s] = Cand[q][s];
  }
}

// ---------------- Kernel 3: exact f32 rescore of candidates -> top-8, split-parallel ----------------
// grid NQ/64 blocks x 256 threads (4 waves). Thread (ql, sp=tid>>6) scans only split
// sp's candidates; per-split top-8 under the same (score desc, id asc) total order;
// the 4 sorted lists merge through LDS with the identical comparator.
__global__ __launch_bounds__(256) void rescore8(
    const float* __restrict__ qf, const float* __restrict__ mk,
    const int* __restrict__ fcand, const int* __restrict__ fcnt,
    int* __restrict__ f8) {
  __shared__ float Ssc[64][4][8];   // 8192 B
  __shared__ int   Sid[64][4][8];   // 8192 B
  const int tid = threadIdx.x;
  const int ql = tid & 63, sp = tid >> 6;
  const int qid = blockIdx.x * 64 + ql;
  float q[64];
#pragma unroll
  for (int c = 0; c < 16; ++c) {
    float4 v4 = *(const float4*)(qf + (size_t)qid * HD + 4 * c);
    q[4*c]=v4.x; q[4*c+1]=v4.y; q[4*c+2]=v4.z; q[4*c+3]=v4.w;
  }
  float sc[TK]; int id[TK];
#pragma unroll
  for (int r = 0; r < TK; ++r) { sc[r] = -3.0e38f; id[r] = 0x7fffffff; }
  int cnt = fcnt[(size_t)sp * NQ + qid];
  if (cnt > CAP) cnt = CAP;
#pragma unroll 1
  for (int c = 0; c < cnt; ++c) {
    int kidx = fcand[((size_t)sp * NQ + qid) * CAP + c] & (Mm - 1);
    const float4* kr = (const float4*)(mk + (size_t)kidx * HD);
    float a0 = 0, a1 = 0, a2 = 0, a3 = 0;
#pragma unroll
    for (int cc = 0; cc < 16; ++cc) {
      float4 kv = kr[cc];
      a0 += q[4*cc]*kv.x; a1 += q[4*cc+1]*kv.y; a2 += q[4*cc+2]*kv.z; a3 += q[4*cc+3]*kv.w;
    }
    float s = (a0 + a1) + (a2 + a3);
    if (s > sc[TK - 1] || (s == sc[TK - 1] && kidx < id[TK - 1])) {
      sc[TK - 1] = s; id[TK - 1] = kidx;
#pragma unroll
      for (int p = TK - 1; p > 0; --p) {
        bool sw = (sc[p] > sc[p - 1]) || (sc[p] == sc[p - 1] && id[p] < id[p - 1]);
        if (sw) {
          float ts = sc[p]; sc[p] = sc[p - 1]; sc[p - 1] = ts;
          int   ti = id[p]; id[p] = id[p - 1]; id[p - 1] = ti;
        }
      }
    }
  }
#pragma unroll
  for (int r = 0; r < TK; ++r) { Ssc[ql][sp][r] = sc[r]; Sid[ql][sp][r] = id[r]; }
  __syncthreads();
  if (tid < 64) {
    float mc[TK]; int mi[TK];
#pragma unroll
    for (int r = 0; r < TK; ++r) { mc[r] = -3.0e38f; mi[r] = 0x7fffffff; }
#pragma unroll
    for (int s2 = 0; s2 < 4; ++s2) {
#pragma unroll
      for (int r = 0; r < TK; ++r) {
        float v = Ssc[tid][s2][r];
        int  vi = Sid[tid][s2][r];
        if (v > mc[TK - 1] || (v == mc[TK - 1] && vi < mi[TK - 1])) {
          mc[TK - 1] = v; mi[TK - 1] = vi;
#pragma unroll
          for (int p = TK - 1; p > 0; --p) {
            bool sw = (mc[p] > mc[p - 1]) || (mc[p] == mc[p - 1] && mi[p] < mi[p - 1]);
            if (sw) {
              float ts = mc[p]; mc[p] = mc[p - 1]; mc[p - 1] = ts;
              int   ti = mi[p]; mi[p] = mi[p - 1]; mi[p - 1] = ti;
            }
          }
        }
      }
    }
    const int qo = blockIdx.x * 64 + tid;
#pragma unroll
    for (int r = 0; r < TK; ++r) f8[(size_t)qo * TK + r] = mi[r] & (Mm - 1);
  }
}

// ---------------- Kernel 4: unified MFMA flash attention (mem gather + local causal) ----------------
// grid (8 qt, 32 bh, 4 chunk), block 256 (4 waves). 1024 blocks = 4/CU matching the
// LDS/VGPR residency cap. Local causal tiles on chunk 0 (dispatched first -> no tail).
// Chunk 3's O-accumulator aliases the free FCAND tail. P exchange fully in-register.
__global__ __launch_bounds__(256) void flash_mfma(
    const bf16_t* __restrict__ qh, const bf16_t* __restrict__ ql,
    const bf16_t* __restrict__ kh2, const bf16_t* __restrict__ kl2,
    const bf16_t* __restrict__ vh2, const bf16_t* __restrict__ vl2,
    const bf16_t* __restrict__ khg, const bf16_t* __restrict__ gkl,
    const bf16_t* __restrict__ gvh, const bf16_t* __restrict__ gvl,
    const int* __restrict__ f8, float* __restrict__ ml, float* __restrict__ pacc,
    float* __restrict__ pa3) {
  __shared__ __align__(16) bf16_t KH[64][72];    // 9216 B
  __shared__ __align__(16) bf16_t KL[64][72];    // 9216 B
  __shared__ __align__(16) bf16_t VTH[64][68];   // 8704 B: V^T hi bf16, stride 68
  __shared__ __align__(16) bf16_t VTL[64][68];   // 8704 B   (total 35840 -> 4 blocks/CU)

  const int tid = threadIdx.x;
  const int lane = tid & 63, w = tid >> 6;
  const int l15 = lane & 15, quad = lane >> 4;
  const int qt = blockIdx.x, bh = blockIdx.y, chunk = blockIdx.z;
  const int il = qt * 64 + w * 16 + l15;
  const int qid = bh * Ls + il;
  const bf16x8 qh0 = *(const bf16x8*)(qh + (size_t)qid * HD + quad * 8);
  const bf16x8 qh1 = *(const bf16x8*)(qh + (size_t)qid * HD + 32 + quad * 8);
  const bf16x8 ql0 = *(const bf16x8*)(ql + (size_t)qid * HD + quad * 8);
  const bf16x8 ql1 = *(const bf16x8*)(ql + (size_t)qid * HD + 32 + quad * 8);

  f32x4 O[4] = {};
  float m = -3.0e38f, lsum = 0.f;
  const float scale = 0.125f;
  const int tbase = chunk * 16;                       // mem tile base: 0/16/32/48
  constexpr int nmem = 16;                            // mem tiles per chunk
  const int ntiles = (chunk == 0) ? 17 + qt : 16;     // + local causal tiles on chunk 0
  const int skey = tid >> 2, spart = tid & 3;         // K staging: 1 key x 16 dims
  const int kpair = tid & 31, dgroup = tid >> 5;      // V staging: 2 keys x 8 dims

  bf16x8 kA0, kA1, kB0, kB1;        // K hi/lo fragments for staging
  bf16x8 vha, vhb, vla, vlb;        // raw V rows (2 keys x 8 dims, hi/lo)
  bf16x2 vth[8], vtl[8];            // packed transposed V pairs
  auto stage_load = [&](int t) {
    const bf16_t *ksh, *ksl, *vah, *val_, *vbh, *vbl;
    if (chunk == 0 && t >= nmem) {
      int jlK = (t - nmem) * 64 + skey;
      size_t ro = ((size_t)bh * Ls + jlK) * HD + spart * 16;
      ksh = kh2 + ro; ksl = kl2 + ro;
      int jlV = (t - nmem) * 64 + 2 * kpair;
      size_t ra = ((size_t)bh * Ls + jlV) * HD + dgroup * 8;
      vah = vh2 + ra;      val_ = vl2 + ra;
      vbh = vh2 + ra + HD; vbl  = vl2 + ra + HD;
    } else {
      int jgK = (tbase + t) * 64 + skey;
      int sK = f8[((size_t)bh * Ls + (jgK >> 3)) * TK + (jgK & 7)] & (Mm - 1);
      size_t ro = (size_t)sK * HD + spart * 16;
      ksh = khg + ro; ksl = gkl + ro;
      int jgV = (tbase + t) * 64 + 2 * kpair;          // even -> pair stays in one f8 row
      int2 s2 = *(const int2*)(f8 + ((size_t)bh * Ls + (jgV >> 3)) * TK + (jgV & 7));
      size_t ra = (size_t)(s2.x & (Mm - 1)) * HD + dgroup * 8;
      size_t rb = (size_t)(s2.y & (Mm - 1)) * HD + dgroup * 8;
      vah = gvh + ra; val_ = gvl + ra;
      vbh = gvh + rb; vbl  = gvl + rb;
    }
    kA0 = *(const bf16x8*)ksh; kA1 = *(const bf16x8*)(ksh + 8);
    kB0 = *(const bf16x8*)ksl; kB1 = *(const bf16x8*)(ksl + 8);
    vha = *(const bf16x8*)vah; vla = *(const bf16x8*)val_;
    vhb = *(const bf16x8*)vbh; vlb = *(const bf16x8*)vbl;
  };
  auto pack_v = [&]() {
#pragma unroll
    for (int j = 0; j < 8; ++j) {
      vth[j][0] = vha[j]; vth[j][1] = vhb[j];
      vtl[j][0] = vla[j]; vtl[j][1] = vlb[j];
    }
  };
  stage_load(0);
  pack_v();

  for (int tile = 0; tile < ntiles; ++tile) {
    const bool local_tile = (chunk == 0) && (tile >= nmem);
    __syncthreads();
    {
      *(bf16x8*)&KH[skey][spart * 16]     = kA0;
      *(bf16x8*)&KH[skey][spart * 16 + 8] = kA1;
      *(bf16x8*)&KL[skey][spart * 16]     = kB0;
      *(bf16x8*)&KL[skey][spart * 16 + 8] = kB1;
#pragma unroll
      for (int j = 0; j < 8; ++j) {
        *(bf16x2*)&VTH[dgroup * 8 + j][2 * kpair] = vth[j];
        *(bf16x2*)&VTL[dgroup * 8 + j][2 * kpair] = vtl[j];
      }
    }
    __syncthreads();
    if (tile + 1 < ntiles) stage_load(tile + 1);   // overlap next-tile HBM with compute

    f32x4 S[4];
    __builtin_amdgcn_s_setprio(1);
#pragma unroll
    for (int sub = 0; sub < 4; ++sub) {
      const bf16x8 ah0 = *(const bf16x8*)&KH[sub * 16 + l15][quad * 8];
      const bf16x8 ah1 = *(const bf16x8*)&KH[sub * 16 + l15][32 + quad * 8];
      const bf16x8 al0 = *(const bf16x8*)&KL[sub * 16 + l15][quad * 8];
      const bf16x8 al1 = *(const bf16x8*)&KL[sub * 16 + l15][32 + quad * 8];
      f32x4 acc = {0.f, 0.f, 0.f, 0.f};
      acc = MFMA16(ah0, qh0, acc, 0, 0, 0);
      acc = MFMA16(ah1, qh1, acc, 0, 0, 0);
      acc = MFMA16(al0, qh0, acc, 0, 0, 0);
      acc = MFMA16(al1, qh1, acc, 0, 0, 0);
      acc = MFMA16(ah0, ql0, acc, 0, 0, 0);
      acc = MFMA16(ah1, ql1, acc, 0, 0, 0);
#pragma unroll
      for (int r = 0; r < 4; ++r) {
        float sv = acc[r] * scale;
        if (local_tile && ((tile - nmem) * 64 + sub * 16 + quad * 4 + r) > il) sv = -3.0e38f;
        S[sub][r] = sv;
      }
    }
    __builtin_amdgcn_s_setprio(0);
    float tm = -3.0e38f;
#pragma unroll
    for (int sub = 0; sub < 4; ++sub)
#pragma unroll
      for (int r = 0; r < 4; ++r) tm = fmaxf(tm, S[sub][r]);
    tm = fmaxf(tm, __shfl_xor(tm, 16));
    tm = fmaxf(tm, __shfl_xor(tm, 32));
    float mnew = fmaxf(m, tm);
    float alpha = __expf(m - mnew);
    lsum *= alpha;
#pragma unroll
    for (int t = 0; t < 4; ++t) O[t] *= alpha;
    m = mnew;

    // P computation: pack each sub's 4 bf16 hi/lo into u64 registers (static indexing)
    unsigned long long ph64[4], pl64[4];
#pragma unroll
    for (int sub = 0; sub < 4; ++sub) {
      bf16_t ph4[4], pl4[4];
#pragma unroll
      for (int r = 0; r < 4; ++r) {
        float p = __expf(S[sub][r] - mnew);
        lsum += p;
        bf16_t hv = (bf16_t)p;
        ph4[r] = hv;
        pl4[r] = (bf16_t)(p - (float)hv);
      }
      unsigned long long th, tl;
      __builtin_memcpy(&th, ph4, 8);
      __builtin_memcpy(&tl, pl4, 8);
      ph64[sub] = th; pl64[sub] = tl;
    }
    // In-register exchange within the 4-lane column group (replaces PH/PL LDS):
    // target (l15,quad) needs keys quad*8..+7 (frag 0) and 32+quad*8..+7 (frag 1) of
    // query l15. Owners: oA=(quad&1)*2 (keys j=0..3), oB=oA+1 (j=4..7); subs slo=quad>>1,
    // shi=2+slo. Done hi-THEN-lo with reused temps: peak live shfl temps = 8 u64.
    const int srcA = ((quad & 1) << 5) + l15;   // lane of owner quad oA
    const int srcB = srcA + 16;                 // lane of owner quad oB
    const bool hsel = (quad & 2) != 0;          // slo = quad>>1
    bf16x8 ph0, ph1, pl0, pl1;
    {
      unsigned long long tA0 = __shfl(ph64[0], srcA), tA1 = __shfl(ph64[1], srcA);
      unsigned long long tA2 = __shfl(ph64[2], srcA), tA3 = __shfl(ph64[3], srcA);
      unsigned long long tB0 = __shfl(ph64[0], srcB), tB1 = __shfl(ph64[1], srcB);
      unsigned long long tB2 = __shfl(ph64[2], srcB), tB3 = __shfl(ph64[3], srcB);
      ph0 = cat8(hsel ? tA1 : tA0, hsel ? tB1 : tB0);
      ph1 = cat8(hsel ? tA3 : tA2, hsel ? tB3 : tB2);
    }
    {
      unsigned long long tA0 = __shfl(pl64[0], srcA), tA1 = __shfl(pl64[1], srcA);
      unsigned long long tA2 = __shfl(pl64[2], srcA), tA3 = __shfl(pl64[3], srcA);
      unsigned long long tB0 = __shfl(pl64[0], srcB), tB1 = __shfl(pl64[1], srcB);
      unsigned long long tB2 = __shfl(pl64[2], srcB), tB3 = __shfl(pl64[3], srcB);
      pl0 = cat8(hsel ? tA1 : tA0, hsel ? tB1 : tB0);
      pl1 = cat8(hsel ? tA3 : tA2, hsel ? tB3 : tB2);
    }

    __builtin_amdgcn_s_setprio(1);
#pragma unroll
    for (int t = 0; t < 4; ++t) {
      const bf16x8 vh0 = ld8h(&VTH[t * 16 + l15][quad * 8]);
      const bf16x8 vh1 = ld8h(&VTH[t * 16 + l15][32 + quad * 8]);
      const bf16x8 vl0 = ld8h(&VTL[t * 16 + l15][quad * 8]);
      const bf16x8 vl1 = ld8h(&VTL[t * 16 + l15][32 + quad * 8]);
      O[t] = MFMA16(vh0, ph0, O[t], 0, 0, 0);
      O[t] = MFMA16(vh1, ph1, O[t], 0, 0, 0);
      O[t] = MFMA16(vl0, ph0, O[t], 0, 0, 0);
      O[t] = MFMA16(vl1, ph1, O[t], 0, 0, 0);
      O[t] = MFMA16(vh0, pl0, O[t], 0, 0, 0);
      O[t] = MFMA16(vh1, pl1, O[t], 0, 0, 0);
    }
    __builtin_amdgcn_s_setprio(0);
    if (tile + 1 < ntiles) pack_v();               // pack next V after loads have landed
  }
  lsum += __shfl_xor(lsum, 16);
  lsum += __shfl_xor(lsum, 32);
  if (quad == 0) {
    ml[((size_t)chunk * NQ + qid) * 2 + 0] = m;
    ml[((size_t)chunk * NQ + qid) * 2 + 1] = lsum;
  }
  float* pa = (chunk == 3) ? (pa3 + (size_t)qid * 64)
                           : (pacc + ((size_t)chunk * NQ + qid) * 64);
#pragma unroll
  for (int t = 0; t < 4; ++t) {
    float4 v4; v4.x = O[t][0]; v4.y = O[t][1]; v4.z = O[t][2]; v4.w = O[t][3];
    *(float4*)(pa + t * 16 + quad * 4) = v4;
  }
}

// ---------------- Kernel 5: O-projection, fused 4-way LSE combine, W-tile LDS staged ----------------
__global__ __launch_bounds__(256) void oproj_comb(
    const float* __restrict__ ml, const float* __restrict__ pacc,
    const float* __restrict__ pa3,
    const float* __restrict__ Wo, const float* __restrict__ bo,
    float* __restrict__ out) {
  __shared__ __align__(16) bf16_t WHs[2][64][40];
  __shared__ __align__(16) bf16_t WLs[2][64][40];
  const int tid = threadIdx.x;
  const int lane = tid & 63, wv = tid >> 6;
  const int l15 = lane & 15, quad = lane >> 4;
  const int mrow = blockIdx.x * 64 + wv * 16 + l15;    // token row 0..1023
  const int b = mrow >> 9, l = mrow & 511;
  const int ncol0 = blockIdx.y * 64;
  const int srow = tid >> 2, scol = (tid & 3) * 8;
  const size_t wbase = (size_t)(ncol0 + srow) * Dd + scol;
  f32x4 acc[4] = {};
  {
    float wv8[8]; ld8f(Wo + wbase, wv8);
    bf16x8 h, l2; split8(wv8, h, l2);
    *(bf16x8*)&WHs[0][srow][scol] = h;
    *(bf16x8*)&WLs[0][srow][scol] = l2;
  }
  int p = 0;
  for (int kk = 0; kk < Dd; kk += 32) {
    __syncthreads();
    if (kk + 32 < Dd) {
      float wv8[8]; ld8f(Wo + wbase + kk + 32, wv8);
      bf16x8 h, l2; split8(wv8, h, l2);
      *(bf16x8*)&WHs[p ^ 1][srow][scol] = h;
      *(bf16x8*)&WLs[p ^ 1][srow][scol] = l2;
    }
    const int h = kk >> 6;
    const size_t qid = (size_t)(b * Hh + h) * Ls + l;
    float m0 = ml[qid * 2 + 0],                    l0 = ml[qid * 2 + 1];
    float m1 = ml[((size_t)NQ + qid) * 2 + 0],     l1 = ml[((size_t)NQ + qid) * 2 + 1];
    float m2 = ml[((size_t)2 * NQ + qid) * 2 + 0], l2v = ml[((size_t)2 * NQ + qid) * 2 + 1];
    float m3 = ml[((size_t)3 * NQ + qid) * 2 + 0], l3v = ml[((size_t)3 * NQ + qid) * 2 + 1];
    float M = fmaxf(fmaxf(m0, m1), fmaxf(m2, m3));
    float w0 = __expf(m0 - M), w1 = __expf(m1 - M), w2 = __expf(m2 - M), w3 = __expf(m3 - M);
    float inv = 1.f / (w0 * l0 + w1 * l1 + w2 * l2v + w3 * l3v);
    const int d0 = (kk & 63) + quad * 8;
    float a0v[8], a1v[8], a2v[8], a3v[8], av[8];
    ld8f(pacc + qid * 64 + d0, a0v);
    ld8f(pacc + ((size_t)NQ + qid) * 64 + d0, a1v);
    ld8f(pacc + ((size_t)2 * NQ + qid) * 64 + d0, a2v);
    ld8f(pa3 + qid * 64 + d0, a3v);
#pragma unroll
    for (int j = 0; j < 8; ++j)
      av[j] = (w0 * a0v[j] + w1 * a1v[j] + w2 * a2v[j] + w3 * a3v[j]) * inv;
    bf16x8 ahi, alo; split8(av, ahi, alo);
#pragma unroll
    for (int t = 0; t < 4; ++t) {
      const bf16x8 whi = *(const bf16x8*)&WHs[p][t * 16 + l15][quad * 8];
      const bf16x8 wlo = *(const bf16x8*)&WLs[p][t * 16 + l15][quad * 8];
      acc[t] = MFMA16(ahi, whi, acc[t], 0, 0, 0);
      acc[t] = MFMA16(alo, whi, acc[t], 0, 0, 0);
      acc[t] = MFMA16(ahi, wlo, acc[t], 0, 0, 0);
    }
    p ^= 1;
  }
#pragma unroll
  for (int t = 0; t < 4; ++t) {
    int col = ncol0 + t * 16 + l15;
    float bb = bo[col];
#pragma unroll
    for (int r = 0; r < 4; ++r) {
      int row = blockIdx.x * 64 + wv * 16 + quad * 4 + r;
      out[(size_t)row * Dd + col] = acc[t][r] + bb;
    }
  }
}

extern "C" void kernel_launch(void* const* d_in, const int* in_sizes, int n_in,
                              void* d_out, int out_size, void* d_ws, size_t ws_size,
                              hipStream_t stream) {
  (void)in_sizes; (void)n_in;
  const float* x  = (const float*)d_in[0];
  const float* mk = (const float*)d_in[1];
  const float* mv = (const float*)d_in[2];
  const float* Wq = (const float*)d_in[3];
  const float* bq = (const float*)d_in[4];
  const float* Wk = (const float*)d_in[5];
  const float* bk = (const float*)d_in[6];
  const float* Wv = (const float*)d_in[7];
  const float* bv = (const float*)d_in[8];
  const float* Wo = (const float*)d_in[9];
  const float* bo = (const float*)d_in[10];
  float* ws = (float*)d_ws;

  if (ws_size < WS_BYTES) {   // constant per-problem -> graph-safe
    float v = (float)(ws_size >> 20) + 0.5f;
    ws_sentinel<<<(out_size + 255) / 256, 256, 0, stream>>>((float*)d_out, out_size, v);
    return;
  }

  float*  QF    = ws + OFF_QF;
  bf16_t* KH2   = (bf16_t*)(ws + OFF_KH2);
  bf16_t* KL2   = (bf16_t*)(ws + OFF_KL2);
  bf16_t* VH2   = (bf16_t*)(ws + OFF_VH2);
  bf16_t* VL2   = (bf16_t*)(ws + OFF_VL2);
  bf16_t* QH    = (bf16_t*)(ws + OFF_QH);
  bf16_t* QL    = (bf16_t*)(ws + OFF_QL);
  bf16_t* KHG   = (bf16_t*)(ws + OFF_KHG);
  int*    FCAND = (int*)(ws + OFF_FCAND);
  int*    FCNT  = (int*)(ws + OFF_FCNT);
  int*    F8    = (int*)(ws + OFF_F8);
  float*  ML    = ws + OFF_ML;
  float*  PA    = ws + OFF_PA;
  bf16_t* XH    = (bf16_t*)(ws + OFF_XH);
  bf16_t* XL    = (bf16_t*)(ws + OFF_XL);
  bf16_t* GKL   = (bf16_t*)(ws + OFF_GKL);
  bf16_t* GVH   = (bf16_t*)(ws + OFF_GVH);
  bf16_t* GVL   = (bf16_t*)(ws + OFF_GVL);
  float*  PA3   = ws + OFF_PA3;

  prep_keys<<<(Mm * HD) / (256 * 8), 256, 0, stream>>>(mk, KHG);
  prep_x<<<(Bb * Ls * Dd) / (256 * 8), 256, 0, stream>>>(x, XH, XL);
  qkv_mfma<<<dim3(16, 16, 3), 256, 0, stream>>>(XH, XL, Wq, bq, Wk, bk, Wv, bv,
                                                QF, QH, QL, KH2, KL2, VH2, VL2);
  topk_thresh<<<dim3(NQ / 64, KSPLIT), 256, 0, stream>>>(QH, KHG, FCAND, FCNT);
  rescore8<<<NQ / 64, 256, 0, stream>>>(QF, mk, FCAND, FCNT, F8);
  prep_kv2<<<(Mm * HD) / (256 * 8), 256, 0, stream>>>(mk, mv, GKL, GVH, GVL);
  flash_mfma<<<dim3(8, 32, 4), 256, 0, stream>>>(QH, QL, KH2, KL2, VH2, VL2,
                                                 KHG, GKL, GVH, GVL, F8, ML, PA, PA3);
  oproj_comb<<<dim3(16, 16), 256, 0, stream>>>(ML, PA, PA3, Wo, bo, (float*)d_out);
}